// Round 1
// baseline (2163.960 us; speedup 1.0000x reference)
//
#include <hip/hip_runtime.h>

#define NNODES 100000
#define NEDGES 1600000
#define NFEAT  256
#define NHID   128
#define NCLASS 41

// ---------- degree: deg[dst] += w (edges only; self-loop +1 folded into k_dinv) ----------
__global__ __launch_bounds__(256) void k_deg(const int* __restrict__ dst, const float* __restrict__ w,
                                             float* __restrict__ deg) {
    int e = blockIdx.x * 256 + threadIdx.x;
    if (e < NEDGES) atomicAdd(&deg[dst[e]], w[e]);
}

// ---------- dinv[i] = rsqrt(deg[i] + 1)  (deg+1 >= 1 > 0 always) ----------
__global__ __launch_bounds__(256) void k_dinv(float* __restrict__ deg) {
    int i = blockIdx.x * 256 + threadIdx.x;
    if (i < NNODES) deg[i] = rsqrtf(deg[i] + 1.0f);
}

// ---------- norm[e] = dinv[src]*w*dinv[dst] ----------
__global__ __launch_bounds__(256) void k_norm(const int* __restrict__ src, const int* __restrict__ dst,
                                              const float* __restrict__ w, const float* __restrict__ dinv,
                                              float* __restrict__ norm) {
    int e = blockIdx.x * 256 + threadIdx.x;
    if (e < NEDGES) norm[e] = dinv[src[e]] * w[e] * dinv[dst[e]];
}

// ---------- GEMM1: h1[N,128] = x[N,256] @ W1[256,128], fp32, 128x128 tile ----------
__global__ __launch_bounds__(256) void k_gemm1(const float* __restrict__ x, const float* __restrict__ W1,
                                               float* __restrict__ h1) {
    __shared__ float At[32][132];   // transposed A tile: At[k][row], padded stride
    __shared__ float Bs[32][128];
    const int tid = threadIdx.x;
    const int m0  = blockIdx.x * 128;
    const int tx  = tid & 15;       // cols tx*8 .. +7
    const int ty  = tid >> 4;       // rows ty*8 .. +7
    float acc[8][8];
#pragma unroll
    for (int r = 0; r < 8; ++r)
#pragma unroll
        for (int c = 0; c < 8; ++c) acc[r][c] = 0.f;

    for (int k0 = 0; k0 < NFEAT; k0 += 32) {
        // stage A (128 rows x 32 k): 4 float4 per thread, store transposed
#pragma unroll
        for (int i = 0; i < 4; ++i) {
            int idx = tid + i * 256;
            int row = idx >> 3, c4 = idx & 7;
            float4 v = make_float4(0.f, 0.f, 0.f, 0.f);
            int gr = m0 + row;
            if (gr < NNODES) v = *(const float4*)(x + gr * NFEAT + k0 + c4 * 4);
            At[c4 * 4 + 0][row] = v.x;
            At[c4 * 4 + 1][row] = v.y;
            At[c4 * 4 + 2][row] = v.z;
            At[c4 * 4 + 3][row] = v.w;
        }
        // stage B (32 k x 128 cols): 4 float4 per thread
#pragma unroll
        for (int i = 0; i < 4; ++i) {
            int idx = tid + i * 256;
            int kr = idx >> 5, c4 = idx & 31;
            *(float4*)(&Bs[kr][c4 * 4]) = *(const float4*)(W1 + (k0 + kr) * NHID + c4 * 4);
        }
        __syncthreads();
#pragma unroll
        for (int kk = 0; kk < 32; ++kk) {
            float4 a0 = *(const float4*)(&At[kk][ty * 8]);
            float4 a1 = *(const float4*)(&At[kk][ty * 8 + 4]);
            float4 b0 = *(const float4*)(&Bs[kk][tx * 8]);
            float4 b1 = *(const float4*)(&Bs[kk][tx * 8 + 4]);
            float a[8] = {a0.x, a0.y, a0.z, a0.w, a1.x, a1.y, a1.z, a1.w};
            float b[8] = {b0.x, b0.y, b0.z, b0.w, b1.x, b1.y, b1.z, b1.w};
#pragma unroll
            for (int r = 0; r < 8; ++r)
#pragma unroll
                for (int c = 0; c < 8; ++c) acc[r][c] += a[r] * b[c];
        }
        __syncthreads();
    }
#pragma unroll
    for (int r = 0; r < 8; ++r) {
        int gr = m0 + ty * 8 + r;
        if (gr < NNODES) {
            *(float4*)(h1 + gr * NHID + tx * 8)     = make_float4(acc[r][0], acc[r][1], acc[r][2], acc[r][3]);
            *(float4*)(h1 + gr * NHID + tx * 8 + 4) = make_float4(acc[r][4], acc[r][5], acc[r][6], acc[r][7]);
        }
    }
}

// ---------- agg1: agg1[dst] += norm * h1[src]  (wave per edge, float2 per lane) ----------
__global__ __launch_bounds__(256) void k_agg1(const int* __restrict__ src, const int* __restrict__ dst,
                                              const float* __restrict__ norm, const float* __restrict__ h1,
                                              float* __restrict__ agg1) {
    int wid  = (blockIdx.x * 256 + threadIdx.x) >> 6;
    int lane = threadIdx.x & 63;
    int nw   = (gridDim.x * 256) >> 6;
    for (int e = wid; e < NEDGES; e += nw) {
        int s = src[e], d = dst[e];
        float nrm = norm[e];
        float2 hv = *(const float2*)(h1 + s * NHID + lane * 2);
        atomicAdd(&agg1[d * NHID + lane * 2],     nrm * hv.x);
        atomicAdd(&agg1[d * NHID + lane * 2 + 1], nrm * hv.y);
    }
}

// ---------- GEMM2 fused: h2 = relu(agg1 + dinv^2*h1 + b1) @ W2  (thread per row) ----------
__global__ __launch_bounds__(256) void k_gemm2(const float* __restrict__ agg1, const float* __restrict__ h1,
                                               const float* __restrict__ dinv, const float* __restrict__ b1,
                                               const float* __restrict__ W2, float* __restrict__ h2) {
    int row = blockIdx.x * 256 + threadIdx.x;
    if (row >= NNODES) return;
    float sl = dinv[row];
    sl = sl * sl;
    float acc[NCLASS];
#pragma unroll
    for (int c = 0; c < NCLASS; ++c) acc[c] = 0.f;
    const float* ar = agg1 + row * NHID;
    const float* hr = h1 + row * NHID;
    for (int k = 0; k < NHID; ++k) {
        float xv = ar[k] + sl * hr[k] + b1[k];
        xv = fmaxf(xv, 0.0f);
#pragma unroll
        for (int c = 0; c < NCLASS; ++c) acc[c] += xv * W2[k * NCLASS + c];
    }
    float* o = h2 + row * NCLASS;
#pragma unroll
    for (int c = 0; c < NCLASS; ++c) o[c] = acc[c];
}

// ---------- agg2: out[dst] += norm * h2[src]  (wave per edge, lanes 0..40) ----------
__global__ __launch_bounds__(256) void k_agg2(const int* __restrict__ src, const int* __restrict__ dst,
                                              const float* __restrict__ norm, const float* __restrict__ h2,
                                              float* __restrict__ out) {
    int wid  = (blockIdx.x * 256 + threadIdx.x) >> 6;
    int lane = threadIdx.x & 63;
    int nw   = (gridDim.x * 256) >> 6;
    for (int e = wid; e < NEDGES; e += nw) {
        int s = src[e], d = dst[e];
        float nrm = norm[e];
        if (lane < NCLASS) atomicAdd(&out[d * NCLASS + lane], nrm * h2[s * NCLASS + lane]);
    }
}

// ---------- final: out = log_softmax(out + dinv^2*h2 + b2) ----------
__global__ __launch_bounds__(256) void k_final(float* __restrict__ out, const float* __restrict__ h2,
                                               const float* __restrict__ dinv, const float* __restrict__ b2) {
    int row = blockIdx.x * 256 + threadIdx.x;
    if (row >= NNODES) return;
    float sl = dinv[row];
    sl = sl * sl;
    float v[NCLASS];
    float m = -1e30f;
#pragma unroll
    for (int c = 0; c < NCLASS; ++c) {
        float t = out[row * NCLASS + c] + sl * h2[row * NCLASS + c] + b2[c];
        v[c] = t;
        m = fmaxf(m, t);
    }
    float s = 0.f;
#pragma unroll
    for (int c = 0; c < NCLASS; ++c) s += expf(v[c] - m);
    float ls = logf(s) + m;
#pragma unroll
    for (int c = 0; c < NCLASS; ++c) out[row * NCLASS + c] = v[c] - ls;
}

extern "C" void kernel_launch(void* const* d_in, const int* in_sizes, int n_in,
                              void* d_out, int out_size, void* d_ws, size_t ws_size,
                              hipStream_t stream) {
    const float* x  = (const float*)d_in[0];
    const int*   ei = (const int*)d_in[1];
    const float* ew = (const float*)d_in[2];
    const float* W1 = (const float*)d_in[3];
    const float* b1 = (const float*)d_in[4];
    const float* W2 = (const float*)d_in[5];
    const float* b2 = (const float*)d_in[6];
    float* out = (float*)d_out;
    const int* srcp = ei;            // edge_index[0]
    const int* dstp = ei + NEDGES;   // edge_index[1]

    char* ws = (char*)d_ws;
    auto take = [&](size_t bytes) {
        char* p = ws;
        ws += (bytes + 255) & ~(size_t)255;
        return p;
    };
    float* dinv = (float*)take((size_t)NNODES * 4);
    float* norm = (float*)take((size_t)NEDGES * 4);
    float* h1   = (float*)take((size_t)NNODES * NHID * 4);
    float* agg1 = (float*)take((size_t)NNODES * NHID * 4);
    float* h2   = (float*)take((size_t)NNODES * NCLASS * 4);

    hipMemsetAsync(dinv, 0, (size_t)NNODES * 4, stream);
    hipMemsetAsync(agg1, 0, (size_t)NNODES * NHID * 4, stream);
    hipMemsetAsync(out, 0, (size_t)NNODES * NCLASS * 4, stream);

    k_deg<<<(NEDGES + 255) / 256, 256, 0, stream>>>(dstp, ew, dinv);
    k_dinv<<<(NNODES + 255) / 256, 256, 0, stream>>>(dinv);
    k_norm<<<(NEDGES + 255) / 256, 256, 0, stream>>>(srcp, dstp, ew, dinv, norm);
    k_gemm1<<<(NNODES + 127) / 128, 256, 0, stream>>>(x, W1, h1);
    k_agg1<<<4096, 256, 0, stream>>>(srcp, dstp, norm, h1, agg1);
    k_gemm2<<<(NNODES + 255) / 256, 256, 0, stream>>>(agg1, h1, dinv, b1, W2, h2);
    k_agg2<<<4096, 256, 0, stream>>>(srcp, dstp, norm, h2, out);
    k_final<<<(NNODES + 255) / 256, 256, 0, stream>>>(out, h2, dinv, b2);
}

// Round 2
// 926.290 us; speedup vs baseline: 2.3362x; 2.3362x over previous
//
#include <hip/hip_runtime.h>

#define NNODES 100000
#define NEDGES 1600000
#define NFEAT  256
#define NHID   128
#define NCLASS 41
#define SCAN_B 256
#define NB1    ((NNODES + SCAN_B - 1) / SCAN_B)   // 391 scan blocks

// ---------- hist: weighted degree (float) + in-degree count (int) ----------
__global__ __launch_bounds__(256) void k_hist(const int* __restrict__ dst, const float* __restrict__ w,
                                              float* __restrict__ deg, int* __restrict__ cnt) {
    int e = blockIdx.x * 256 + threadIdx.x;
    if (e < NEDGES) {
        int d = dst[e];
        atomicAdd(&deg[d], w[e]);
        atomicAdd(&cnt[d], 1);
    }
}

// ---------- dinv[i] = rsqrt(deg[i] + 1)  (self-loop weight 1 folded in) ----------
__global__ __launch_bounds__(256) void k_dinv(float* __restrict__ deg) {
    int i = blockIdx.x * 256 + threadIdx.x;
    if (i < NNODES) deg[i] = rsqrtf(deg[i] + 1.0f);
}

// ---------- scan level 1: per-block inclusive scan of cnt, save block totals ----------
__global__ __launch_bounds__(SCAN_B) void k_scan1(const int* __restrict__ cnt, int* __restrict__ incl,
                                                  int* __restrict__ bsum) {
    __shared__ int sm[SCAN_B];
    int i = blockIdx.x * SCAN_B + threadIdx.x;
    int v = (i < NNODES) ? cnt[i] : 0;
    sm[threadIdx.x] = v;
    __syncthreads();
    for (int o = 1; o < SCAN_B; o <<= 1) {
        int t = (threadIdx.x >= (unsigned)o) ? sm[threadIdx.x - o] : 0;
        __syncthreads();
        sm[threadIdx.x] += t;
        __syncthreads();
    }
    if (i < NNODES) incl[i] = sm[threadIdx.x];
    if (threadIdx.x == SCAN_B - 1) bsum[blockIdx.x] = sm[threadIdx.x];
}

// ---------- scan level 2: single block, exclusive scan of 391 block sums in-place ----------
__global__ __launch_bounds__(512) void k_scan2(int* __restrict__ bsum) {
    __shared__ int sm[512];
    int tid = threadIdx.x;
    int v = (tid < NB1) ? bsum[tid] : 0;
    sm[tid] = v;
    __syncthreads();
    for (int o = 1; o < 512; o <<= 1) {
        int t = (tid >= o) ? sm[tid - o] : 0;
        __syncthreads();
        sm[tid] += t;
        __syncthreads();
    }
    if (tid < NB1) bsum[tid] = sm[tid] - v;   // exclusive
}

// ---------- scan level 3: global exclusive rowptr + cursor copy ----------
__global__ __launch_bounds__(256) void k_scan3(const int* __restrict__ incl, const int* __restrict__ cnt,
                                               const int* __restrict__ boff, int* __restrict__ rowptr,
                                               int* __restrict__ cursor) {
    int i = blockIdx.x * 256 + threadIdx.x;
    if (i < NNODES) {
        int ex = incl[i] - cnt[i] + boff[i >> 8];   // SCAN_B == 256
        rowptr[i] = ex;
        cursor[i] = ex;
        if (i == NNODES - 1) rowptr[NNODES] = ex + cnt[i];
    }
}

// ---------- scatter edges into CSR slots; norm computed inline ----------
__global__ __launch_bounds__(256) void k_scatter(const int* __restrict__ src, const int* __restrict__ dst,
                                                 const float* __restrict__ w, const float* __restrict__ dinv,
                                                 int* __restrict__ cursor, int* __restrict__ col,
                                                 float* __restrict__ val) {
    int e = blockIdx.x * 256 + threadIdx.x;
    if (e < NEDGES) {
        int s = src[e], d = dst[e];
        int pos = atomicAdd(&cursor[d], 1);
        col[pos] = s;
        val[pos] = dinv[s] * w[e] * dinv[d];
    }
}

// ---------- GEMM1: h1[N,128] = x[N,256] @ W1[256,128], fp32, 128x128 tile ----------
__global__ __launch_bounds__(256) void k_gemm1(const float* __restrict__ x, const float* __restrict__ W1,
                                               float* __restrict__ h1) {
    __shared__ float At[32][132];
    __shared__ float Bs[32][128];
    const int tid = threadIdx.x;
    const int m0  = blockIdx.x * 128;
    const int tx  = tid & 15;
    const int ty  = tid >> 4;
    float acc[8][8];
#pragma unroll
    for (int r = 0; r < 8; ++r)
#pragma unroll
        for (int c = 0; c < 8; ++c) acc[r][c] = 0.f;

    for (int k0 = 0; k0 < NFEAT; k0 += 32) {
#pragma unroll
        for (int i = 0; i < 4; ++i) {
            int idx = tid + i * 256;
            int row = idx >> 3, c4 = idx & 7;
            float4 v = make_float4(0.f, 0.f, 0.f, 0.f);
            int gr = m0 + row;
            if (gr < NNODES) v = *(const float4*)(x + (size_t)gr * NFEAT + k0 + c4 * 4);
            At[c4 * 4 + 0][row] = v.x;
            At[c4 * 4 + 1][row] = v.y;
            At[c4 * 4 + 2][row] = v.z;
            At[c4 * 4 + 3][row] = v.w;
        }
#pragma unroll
        for (int i = 0; i < 4; ++i) {
            int idx = tid + i * 256;
            int kr = idx >> 5, c4 = idx & 31;
            *(float4*)(&Bs[kr][c4 * 4]) = *(const float4*)(W1 + (size_t)(k0 + kr) * NHID + c4 * 4);
        }
        __syncthreads();
#pragma unroll
        for (int kk = 0; kk < 32; ++kk) {
            float4 a0 = *(const float4*)(&At[kk][ty * 8]);
            float4 a1 = *(const float4*)(&At[kk][ty * 8 + 4]);
            float4 b0 = *(const float4*)(&Bs[kk][tx * 8]);
            float4 b1 = *(const float4*)(&Bs[kk][tx * 8 + 4]);
            float a[8] = {a0.x, a0.y, a0.z, a0.w, a1.x, a1.y, a1.z, a1.w};
            float b[8] = {b0.x, b0.y, b0.z, b0.w, b1.x, b1.y, b1.z, b1.w};
#pragma unroll
            for (int r = 0; r < 8; ++r)
#pragma unroll
                for (int c = 0; c < 8; ++c) acc[r][c] += a[r] * b[c];
        }
        __syncthreads();
    }
#pragma unroll
    for (int r = 0; r < 8; ++r) {
        int gr = m0 + ty * 8 + r;
        if (gr < NNODES) {
            *(float4*)(h1 + (size_t)gr * NHID + tx * 8)     = make_float4(acc[r][0], acc[r][1], acc[r][2], acc[r][3]);
            *(float4*)(h1 + (size_t)gr * NHID + tx * 8 + 4) = make_float4(acc[r][4], acc[r][5], acc[r][6], acc[r][7]);
        }
    }
}

// ---------- agg1 CSR: wave per node; a1 = relu(sum_in + dinv^2*h1[row] + b1) ----------
__global__ __launch_bounds__(256) void k_agg1_csr(const int* __restrict__ rowptr, const int* __restrict__ col,
                                                  const float* __restrict__ val, const float* __restrict__ h1,
                                                  const float* __restrict__ dinv, const float* __restrict__ b1,
                                                  float* __restrict__ a1) {
    int node = (blockIdx.x * 256 + threadIdx.x) >> 6;
    int lane = threadIdx.x & 63;
    if (node >= NNODES) return;
    int beg = rowptr[node], end = rowptr[node + 1];
    float acc0 = 0.f, acc1 = 0.f;
    int j = beg;
    for (; j + 1 < end; j += 2) {          // 2x unroll for latency overlap
        int   s0 = col[j],     s1 = col[j + 1];
        float n0 = val[j],     n1 = val[j + 1];
        float2 hv0 = *(const float2*)(h1 + (size_t)s0 * NHID + lane * 2);
        float2 hv1 = *(const float2*)(h1 + (size_t)s1 * NHID + lane * 2);
        acc0 += n0 * hv0.x + n1 * hv1.x;
        acc1 += n0 * hv0.y + n1 * hv1.y;
    }
    if (j < end) {
        int s = col[j];
        float nv = val[j];
        float2 hv = *(const float2*)(h1 + (size_t)s * NHID + lane * 2);
        acc0 += nv * hv.x;
        acc1 += nv * hv.y;
    }
    float sl = dinv[node];
    sl = sl * sl;
    float2 hs = *(const float2*)(h1 + (size_t)node * NHID + lane * 2);
    float2 bb = *(const float2*)(b1 + lane * 2);
    float r0 = fmaxf(acc0 + sl * hs.x + bb.x, 0.f);
    float r1 = fmaxf(acc1 + sl * hs.y + bb.y, 0.f);
    *(float2*)(a1 + (size_t)node * NHID + lane * 2) = make_float2(r0, r1);
}

// ---------- GEMM2: h2[N,41] = a1[N,128] @ W2[128,41] (thread per row) ----------
__global__ __launch_bounds__(256) void k_gemm2(const float* __restrict__ a1, const float* __restrict__ W2,
                                               float* __restrict__ h2) {
    int row = blockIdx.x * 256 + threadIdx.x;
    if (row >= NNODES) return;
    float acc[NCLASS];
#pragma unroll
    for (int c = 0; c < NCLASS; ++c) acc[c] = 0.f;
    const float* ar = a1 + (size_t)row * NHID;
    for (int k = 0; k < NHID; ++k) {
        float xv = ar[k];
#pragma unroll
        for (int c = 0; c < NCLASS; ++c) acc[c] += xv * W2[k * NCLASS + c];
    }
    float* o = h2 + (size_t)row * NCLASS;
#pragma unroll
    for (int c = 0; c < NCLASS; ++c) o[c] = acc[c];
}

// ---------- agg2 CSR + fused log-softmax: wave per node, lane = class ----------
__global__ __launch_bounds__(256) void k_agg2_csr(const int* __restrict__ rowptr, const int* __restrict__ col,
                                                  const float* __restrict__ val, const float* __restrict__ h2,
                                                  const float* __restrict__ dinv, const float* __restrict__ b2,
                                                  float* __restrict__ out) {
    int node = (blockIdx.x * 256 + threadIdx.x) >> 6;
    int lane = threadIdx.x & 63;
    if (node >= NNODES) return;
    int beg = rowptr[node], end = rowptr[node + 1];
    float acc = 0.f;
    for (int j = beg; j < end; ++j) {
        int s = col[j];
        float nv = val[j];
        if (lane < NCLASS) acc += nv * h2[(size_t)s * NCLASS + lane];
    }
    float sl = dinv[node];
    sl = sl * sl;
    float v = -1e30f;
    if (lane < NCLASS) v = acc + sl * h2[(size_t)node * NCLASS + lane] + b2[lane];
    float m = v;
#pragma unroll
    for (int o = 32; o >= 1; o >>= 1) m = fmaxf(m, __shfl_xor(m, o));
    float ex = (lane < NCLASS) ? expf(v - m) : 0.f;
    float s_ = ex;
#pragma unroll
    for (int o = 32; o >= 1; o >>= 1) s_ += __shfl_xor(s_, o);
    float ls = logf(s_) + m;
    if (lane < NCLASS) out[(size_t)node * NCLASS + lane] = v - ls;
}

extern "C" void kernel_launch(void* const* d_in, const int* in_sizes, int n_in,
                              void* d_out, int out_size, void* d_ws, size_t ws_size,
                              hipStream_t stream) {
    const float* x  = (const float*)d_in[0];
    const int*   ei = (const int*)d_in[1];
    const float* ew = (const float*)d_in[2];
    const float* W1 = (const float*)d_in[3];
    const float* b1 = (const float*)d_in[4];
    const float* W2 = (const float*)d_in[5];
    const float* b2 = (const float*)d_in[6];
    float* out = (float*)d_out;
    const int* srcp = ei;
    const int* dstp = ei + NEDGES;

    char* ws = (char*)d_ws;
    auto take = [&](size_t bytes) {
        char* p = ws;
        ws += (bytes + 255) & ~(size_t)255;
        return p;
    };
    float* dinv   = (float*)take((size_t)NNODES * 4);
    int*   cnt    = (int*)take((size_t)NNODES * 4);
    int*   incl   = (int*)take((size_t)NNODES * 4);
    int*   bsum   = (int*)take((size_t)NB1 * 4);
    int*   rowptr = (int*)take((size_t)(NNODES + 1) * 4);
    int*   cursor = (int*)take((size_t)NNODES * 4);
    int*   col    = (int*)take((size_t)NEDGES * 4);
    float* val    = (float*)take((size_t)NEDGES * 4);
    float* h1     = (float*)take((size_t)NNODES * NHID * 4);
    float* a1     = (float*)take((size_t)NNODES * NHID * 4);
    float* h2     = (float*)take((size_t)NNODES * NCLASS * 4);

    hipMemsetAsync(dinv, 0, (size_t)NNODES * 4, stream);
    hipMemsetAsync(cnt,  0, (size_t)NNODES * 4, stream);

    k_hist<<<(NEDGES + 255) / 256, 256, 0, stream>>>(dstp, ew, dinv, cnt);
    k_dinv<<<(NNODES + 255) / 256, 256, 0, stream>>>(dinv);
    k_scan1<<<NB1, SCAN_B, 0, stream>>>(cnt, incl, bsum);
    k_scan2<<<1, 512, 0, stream>>>(bsum);
    k_scan3<<<(NNODES + 255) / 256, 256, 0, stream>>>(incl, cnt, bsum, rowptr, cursor);
    k_scatter<<<(NEDGES + 255) / 256, 256, 0, stream>>>(srcp, dstp, ew, dinv, cursor, col, val);
    k_gemm1<<<(NNODES + 127) / 128, 256, 0, stream>>>(x, W1, h1);
    k_agg1_csr<<<(NNODES * 64 + 255) / 256, 256, 0, stream>>>(rowptr, col, val, h1, dinv, b1, a1);
    k_gemm2<<<(NNODES + 255) / 256, 256, 0, stream>>>(a1, W2, h2);
    k_agg2_csr<<<(NNODES * 64 + 255) / 256, 256, 0, stream>>>(rowptr, col, val, h2, dinv, b2, out);
}

// Round 3
// 758.190 us; speedup vs baseline: 2.8541x; 1.2217x over previous
//
#include <hip/hip_runtime.h>

#define NNODES 100000
#define NEDGES 1600000
#define NFEAT  256
#define NHID   128
#define NCLASS 41
#define SCAN_B 256
#define NB1    ((NNODES + SCAN_B - 1) / SCAN_B)   // 391 scan blocks

typedef __attribute__((ext_vector_type(8))) short bf16x8;
typedef __attribute__((ext_vector_type(4))) float f32x4;
typedef __attribute__((ext_vector_type(4))) unsigned short us4;
typedef unsigned short u16;
typedef unsigned int u32;

__device__ __forceinline__ float bf2f(u32 bits16) {
    union { u32 i; float f; } v; v.i = bits16 << 16; return v.f;
}
__device__ __forceinline__ u16 f2bf(float f) {            // round-to-nearest-even
    union { u32 i; float f; } v; v.f = f;
    return (u16)((v.i + 0x7fff + ((v.i >> 16) & 1)) >> 16);
}
__device__ __forceinline__ void gload_lds16(const u16* g, u16* l) {
    __builtin_amdgcn_global_load_lds((const __attribute__((address_space(1))) u32*)g,
                                     (__attribute__((address_space(3))) u32*)l, 16, 0, 0);
}

// ---------- hist: weighted degree (float) + in-degree count (int) ----------
__global__ __launch_bounds__(256) void k_hist(const int* __restrict__ dst, const float* __restrict__ w,
                                              float* __restrict__ deg, int* __restrict__ cnt) {
    int e = blockIdx.x * 256 + threadIdx.x;
    if (e < NEDGES) {
        int d = dst[e];
        atomicAdd(&deg[d], w[e]);
        atomicAdd(&cnt[d], 1);
    }
}

// ---------- dinv[i] = rsqrt(deg[i] + 1) ----------
__global__ __launch_bounds__(256) void k_dinv(float* __restrict__ deg) {
    int i = blockIdx.x * 256 + threadIdx.x;
    if (i < NNODES) deg[i] = rsqrtf(deg[i] + 1.0f);
}

// ---------- W1t[n][k] = bf16(W1[k][n]) : pre-transposed bf16 B operand ----------
__global__ __launch_bounds__(256) void k_w1t(const float* __restrict__ W1, u16* __restrict__ W1t) {
    int idx = blockIdx.x * 256 + threadIdx.x;
    if (idx < NFEAT * NHID) {
        int k = idx >> 7, n = idx & 127;
        W1t[n * NFEAT + k] = f2bf(W1[idx]);
    }
}

// ---------- scan level 1 ----------
__global__ __launch_bounds__(SCAN_B) void k_scan1(const int* __restrict__ cnt, int* __restrict__ incl,
                                                  int* __restrict__ bsum) {
    __shared__ int sm[SCAN_B];
    int i = blockIdx.x * SCAN_B + threadIdx.x;
    int v = (i < NNODES) ? cnt[i] : 0;
    sm[threadIdx.x] = v;
    __syncthreads();
    for (int o = 1; o < SCAN_B; o <<= 1) {
        int t = (threadIdx.x >= (unsigned)o) ? sm[threadIdx.x - o] : 0;
        __syncthreads();
        sm[threadIdx.x] += t;
        __syncthreads();
    }
    if (i < NNODES) incl[i] = sm[threadIdx.x];
    if (threadIdx.x == SCAN_B - 1) bsum[blockIdx.x] = sm[threadIdx.x];
}

// ---------- scan level 2 ----------
__global__ __launch_bounds__(512) void k_scan2(int* __restrict__ bsum) {
    __shared__ int sm[512];
    int tid = threadIdx.x;
    int v = (tid < NB1) ? bsum[tid] : 0;
    sm[tid] = v;
    __syncthreads();
    for (int o = 1; o < 512; o <<= 1) {
        int t = (tid >= o) ? sm[tid - o] : 0;
        __syncthreads();
        sm[tid] += t;
        __syncthreads();
    }
    if (tid < NB1) bsum[tid] = sm[tid] - v;
}

// ---------- scan level 3 ----------
__global__ __launch_bounds__(256) void k_scan3(const int* __restrict__ incl, const int* __restrict__ cnt,
                                               const int* __restrict__ boff, int* __restrict__ rowptr,
                                               int* __restrict__ cursor) {
    int i = blockIdx.x * 256 + threadIdx.x;
    if (i < NNODES) {
        int ex = incl[i] - cnt[i] + boff[i >> 8];
        rowptr[i] = ex;
        cursor[i] = ex;
        if (i == NNODES - 1) rowptr[NNODES] = ex + cnt[i];
    }
}

// ---------- scatter edges into CSR slots ----------
__global__ __launch_bounds__(256) void k_scatter(const int* __restrict__ src, const int* __restrict__ dst,
                                                 const float* __restrict__ w, const float* __restrict__ dinv,
                                                 int* __restrict__ cursor, int* __restrict__ col,
                                                 float* __restrict__ val) {
    int e = blockIdx.x * 256 + threadIdx.x;
    if (e < NEDGES) {
        int s = src[e], d = dst[e];
        int pos = atomicAdd(&cursor[d], 1);
        col[pos] = s;
        val[pos] = dinv[s] * w[e] * dinv[d];
    }
}

// ---------- GEMM1 (MFMA bf16): h1[N,128](bf16) = x[N,256] @ W1[256,128] ----------
// 128x128 tile, BK=64, 4 waves (2x2), wave = 64x64 = 4x4 frags of 16x16x32.
// LDS XOR-swizzle (G4): chunk ^= (row&7), 16B granular. B staged via global_load_lds
// with pre-swizzled SOURCE (m173); A reg-staged (fp32->bf16 cvt), T14 split.
__global__ __launch_bounds__(256) void k_gemm1(const float* __restrict__ x, const u16* __restrict__ W1t,
                                               u16* __restrict__ h1) {
    __shared__ u16 Asm[2][8192];   // [128 m][64 k] bf16, swizzled
    __shared__ u16 Bsm[2][8192];   // [128 n][64 k] bf16, swizzled
    const int tid  = threadIdx.x;
    const int lane = tid & 63;
    const int w    = tid >> 6;
    const int wm   = w >> 1, wn = w & 1;
    const int row16 = lane & 15, g = lane >> 4;
    const int m0   = blockIdx.x * 128;
    const int swz  = (row16 & 7) << 3;      // frag-read swizzle (ushort units)

    f32x4 acc[4][4];
#pragma unroll
    for (int i = 0; i < 4; ++i)
#pragma unroll
        for (int j = 0; j < 4; ++j) acc[i][j] = (f32x4){0.f, 0.f, 0.f, 0.f};

    float4 areg[8];

    auto loadA = [&](int k0) {
#pragma unroll
        for (int i = 0; i < 8; ++i) {
            int s = tid + i * 256;          // slot over 2048 float4s
            int row = s >> 4, c4 = s & 15;
            int gr = m0 + row;
            if (gr < NNODES) areg[i] = *(const float4*)(x + (size_t)gr * NFEAT + k0 + c4 * 4);
            else             areg[i] = make_float4(0.f, 0.f, 0.f, 0.f);
        }
    };
    auto writeA = [&](int buf) {
#pragma unroll
        for (int i = 0; i < 8; ++i) {
            int s = tid + i * 256;
            int row = s >> 4, c4 = s & 15;
            int idx = row * 64 + ((c4 * 4) ^ ((row & 7) << 3));
            us4 h;
            h.x = f2bf(areg[i].x); h.y = f2bf(areg[i].y);
            h.z = f2bf(areg[i].z); h.w = f2bf(areg[i].w);
            *(us4*)(&Asm[buf][idx]) = h;
        }
    };
    auto stageB = [&](int buf, int k0) {
#pragma unroll
        for (int it = 0; it < 4; ++it) {
            int lin = w * 2048 + it * 512;              // wave-uniform ushort base
            int n_l = (lin + lane * 8) >> 6;            // 64 ushorts per row
            int c_l = lane & 7;
            int gofs = n_l * NFEAT + k0 + ((c_l ^ (n_l & 7)) << 3);
            gload_lds16(W1t + gofs, &Bsm[buf][lin]);
        }
    };
    auto compute = [&](int buf) {
#pragma unroll
        for (int kk2 = 0; kk2 < 2; ++kk2) {
            bf16x8 af[4], bfr[4];
#pragma unroll
            for (int f = 0; f < 4; ++f) {
                int m_l = wm * 64 + f * 16 + row16;
                af[f]  = *(const bf16x8*)(&Asm[buf][m_l * 64 + ((kk2 * 32 + g * 8) ^ swz)]);
                int n_l = wn * 64 + f * 16 + row16;
                bfr[f] = *(const bf16x8*)(&Bsm[buf][n_l * 64 + ((kk2 * 32 + g * 8) ^ swz)]);
            }
#pragma unroll
            for (int fm = 0; fm < 4; ++fm)
#pragma unroll
                for (int fn = 0; fn < 4; ++fn)
                    acc[fm][fn] = __builtin_amdgcn_mfma_f32_16x16x32_bf16(af[fm], bfr[fn], acc[fm][fn], 0, 0, 0);
        }
    };

    loadA(0);
    stageB(0, 0);
    writeA(0);
    __syncthreads();
    int buf = 0;
    for (int step = 0; step < 4; ++step) {
        if (step < 3) { loadA((step + 1) * 64); stageB(buf ^ 1, (step + 1) * 64); }
        compute(buf);
        if (step < 3) writeA(buf ^ 1);
        __syncthreads();
        buf ^= 1;
    }

    // epilogue: C/D layout col=lane&15, row=(lane>>4)*4+reg (m89-verified)
#pragma unroll
    for (int fm = 0; fm < 4; ++fm) {
        int mg = m0 + wm * 64 + fm * 16 + g * 4;
#pragma unroll
        for (int r = 0; r < 4; ++r) {
            int m_glob = mg + r;
            if (m_glob < NNODES) {
                size_t base = (size_t)m_glob * NHID + wn * 64 + row16;
#pragma unroll
                for (int fn = 0; fn < 4; ++fn)
                    h1[base + fn * 16] = f2bf(acc[fm][fn][r]);
            }
        }
    }
}

// ---------- agg1 CSR (bf16 gather): a1 = bf16(relu(sum_in + dinv^2*h1[row] + b1)) ----------
__global__ __launch_bounds__(256) void k_agg1_csr(const int* __restrict__ rowptr, const int* __restrict__ col,
                                                  const float* __restrict__ val, const u16* __restrict__ h1,
                                                  const float* __restrict__ dinv, const float* __restrict__ b1,
                                                  u16* __restrict__ a1) {
    int node = (blockIdx.x * 256 + threadIdx.x) >> 6;
    int lane = threadIdx.x & 63;
    if (node >= NNODES) return;
    int beg = rowptr[node], end = rowptr[node + 1];
    float acc0 = 0.f, acc1 = 0.f;
    int j = beg;
    for (; j + 1 < end; j += 2) {
        int   s0 = col[j],  s1 = col[j + 1];
        float n0 = val[j],  n1 = val[j + 1];
        u32 u0 = *(const u32*)(h1 + (size_t)s0 * NHID + lane * 2);
        u32 u1 = *(const u32*)(h1 + (size_t)s1 * NHID + lane * 2);
        acc0 += n0 * bf2f(u0 & 0xffff) + n1 * bf2f(u1 & 0xffff);
        acc1 += n0 * bf2f(u0 >> 16)    + n1 * bf2f(u1 >> 16);
    }
    if (j < end) {
        int s = col[j];
        float nv = val[j];
        u32 u = *(const u32*)(h1 + (size_t)s * NHID + lane * 2);
        acc0 += nv * bf2f(u & 0xffff);
        acc1 += nv * bf2f(u >> 16);
    }
    float sl = dinv[node];
    sl = sl * sl;
    u32 us = *(const u32*)(h1 + (size_t)node * NHID + lane * 2);
    float2 bb = *(const float2*)(b1 + lane * 2);
    float r0 = fmaxf(acc0 + sl * bf2f(us & 0xffff) + bb.x, 0.f);
    float r1 = fmaxf(acc1 + sl * bf2f(us >> 16)    + bb.y, 0.f);
    u32 o = (u32)f2bf(r0) | ((u32)f2bf(r1) << 16);
    *(u32*)(a1 + (size_t)node * NHID + lane * 2) = o;
}

// ---------- GEMM2: h2[N,41](fp32) = a1[N,128](bf16) @ W2[128,41] ----------
__global__ __launch_bounds__(256) void k_gemm2(const u16* __restrict__ a1, const float* __restrict__ W2,
                                               float* __restrict__ h2) {
    int row = blockIdx.x * 256 + threadIdx.x;
    if (row >= NNODES) return;
    float acc[NCLASS];
#pragma unroll
    for (int c = 0; c < NCLASS; ++c) acc[c] = 0.f;
    const u16* ar = a1 + (size_t)row * NHID;
    for (int k = 0; k < NHID; k += 4) {
        uint2 u = *(const uint2*)(ar + k);
        float x0 = bf2f(u.x & 0xffff), x1 = bf2f(u.x >> 16);
        float x2 = bf2f(u.y & 0xffff), x3 = bf2f(u.y >> 16);
        const float* w0 = W2 + k * NCLASS;
#pragma unroll
        for (int c = 0; c < NCLASS; ++c)
            acc[c] += x0 * w0[c] + x1 * w0[NCLASS + c] + x2 * w0[2 * NCLASS + c] + x3 * w0[3 * NCLASS + c];
    }
    float* o = h2 + (size_t)row * NCLASS;
#pragma unroll
    for (int c = 0; c < NCLASS; ++c) o[c] = acc[c];
}

// ---------- agg2 CSR + fused log-softmax ----------
__global__ __launch_bounds__(256) void k_agg2_csr(const int* __restrict__ rowptr, const int* __restrict__ col,
                                                  const float* __restrict__ val, const float* __restrict__ h2,
                                                  const float* __restrict__ dinv, const float* __restrict__ b2,
                                                  float* __restrict__ out) {
    int node = (blockIdx.x * 256 + threadIdx.x) >> 6;
    int lane = threadIdx.x & 63;
    if (node >= NNODES) return;
    int beg = rowptr[node], end = rowptr[node + 1];
    float acc = 0.f;
    for (int j = beg; j < end; ++j) {
        int s = col[j];
        float nv = val[j];
        if (lane < NCLASS) acc += nv * h2[(size_t)s * NCLASS + lane];
    }
    float sl = dinv[node];
    sl = sl * sl;
    float v = -1e30f;
    if (lane < NCLASS) v = acc + sl * h2[(size_t)node * NCLASS + lane] + b2[lane];
    float m = v;
#pragma unroll
    for (int o = 32; o >= 1; o >>= 1) m = fmaxf(m, __shfl_xor(m, o));
    float ex = (lane < NCLASS) ? expf(v - m) : 0.f;
    float s_ = ex;
#pragma unroll
    for (int o = 32; o >= 1; o >>= 1) s_ += __shfl_xor(s_, o);
    float ls = logf(s_) + m;
    if (lane < NCLASS) out[(size_t)node * NCLASS + lane] = v - ls;
}

extern "C" void kernel_launch(void* const* d_in, const int* in_sizes, int n_in,
                              void* d_out, int out_size, void* d_ws, size_t ws_size,
                              hipStream_t stream) {
    const float* x  = (const float*)d_in[0];
    const int*   ei = (const int*)d_in[1];
    const float* ew = (const float*)d_in[2];
    const float* W1 = (const float*)d_in[3];
    const float* b1 = (const float*)d_in[4];
    const float* W2 = (const float*)d_in[5];
    const float* b2 = (const float*)d_in[6];
    float* out = (float*)d_out;
    const int* srcp = ei;
    const int* dstp = ei + NEDGES;

    char* ws = (char*)d_ws;
    auto take = [&](size_t bytes) {
        char* p = ws;
        ws += (bytes + 255) & ~(size_t)255;
        return p;
    };
    float* dinv   = (float*)take((size_t)NNODES * 4);
    int*   cnt    = (int*)take((size_t)NNODES * 4);
    int*   incl   = (int*)take((size_t)NNODES * 4);
    int*   bsum   = (int*)take((size_t)NB1 * 4);
    int*   rowptr = (int*)take((size_t)(NNODES + 1) * 4);
    int*   cursor = (int*)take((size_t)NNODES * 4);
    int*   col    = (int*)take((size_t)NEDGES * 4);
    float* val    = (float*)take((size_t)NEDGES * 4);
    u16*   W1t    = (u16*)take((size_t)NFEAT * NHID * 2);
    u16*   h1     = (u16*)take((size_t)NNODES * NHID * 2);
    u16*   a1     = (u16*)take((size_t)NNODES * NHID * 2);
    float* h2     = (float*)take((size_t)NNODES * NCLASS * 4);

    hipMemsetAsync(dinv, 0, (size_t)NNODES * 4, stream);
    hipMemsetAsync(cnt,  0, (size_t)NNODES * 4, stream);

    k_hist<<<(NEDGES + 255) / 256, 256, 0, stream>>>(dstp, ew, dinv, cnt);
    k_dinv<<<(NNODES + 255) / 256, 256, 0, stream>>>(dinv);
    k_w1t<<<(NFEAT * NHID + 255) / 256, 256, 0, stream>>>(W1, W1t);
    k_scan1<<<NB1, SCAN_B, 0, stream>>>(cnt, incl, bsum);
    k_scan2<<<1, 512, 0, stream>>>(bsum);
    k_scan3<<<(NNODES + 255) / 256, 256, 0, stream>>>(incl, cnt, bsum, rowptr, cursor);
    k_scatter<<<(NEDGES + 255) / 256, 256, 0, stream>>>(srcp, dstp, ew, dinv, cursor, col, val);
    k_gemm1<<<(NNODES + 127) / 128, 256, 0, stream>>>(x, W1t, h1);
    k_agg1_csr<<<(NNODES * 64 + 255) / 256, 256, 0, stream>>>(rowptr, col, val, h1, dinv, b1, a1);
    k_gemm2<<<(NNODES + 255) / 256, 256, 0, stream>>>(a1, W2, h2);
    k_agg2_csr<<<(NNODES * 64 + 255) / 256, 256, 0, stream>>>(rowptr, col, val, h2, dinv, b2, out);
}

// Round 4
// 627.853 us; speedup vs baseline: 3.4466x; 1.2076x over previous
//
#include <hip/hip_runtime.h>

#define NNODES 100000
#define NEDGES 1600000
#define NFEAT  256
#define NHID   128
#define NCLASS 41
#define H2S    48          // padded bf16 stride for h2 rows (96 B)
#define SCAN_B 256
#define NB1    ((NNODES + SCAN_B - 1) / SCAN_B)   // 391 scan blocks

typedef __attribute__((ext_vector_type(8))) short bf16x8;
typedef __attribute__((ext_vector_type(4))) float f32x4;
typedef __attribute__((ext_vector_type(4))) unsigned short us4;
typedef unsigned short u16;
typedef unsigned int u32;

__device__ __forceinline__ float bf2f(u32 bits16) {
    union { u32 i; float f; } v; v.i = bits16 << 16; return v.f;
}
__device__ __forceinline__ u16 f2bf(float f) {            // round-to-nearest-even
    union { u32 i; float f; } v; v.f = f;
    return (u16)((v.i + 0x7fff + ((v.i >> 16) & 1)) >> 16);
}
__device__ __forceinline__ void gload_lds16(const u16* g, u16* l) {
    __builtin_amdgcn_global_load_lds((const __attribute__((address_space(1))) u32*)g,
                                     (__attribute__((address_space(3))) u32*)l, 16, 0, 0);
}

// ---------- hist: weighted degree (float) + in-degree count (int) ----------
__global__ __launch_bounds__(256) void k_hist(const int* __restrict__ dst, const float* __restrict__ w,
                                              float* __restrict__ deg, int* __restrict__ cnt) {
    int e = blockIdx.x * 256 + threadIdx.x;
    if (e < NEDGES) {
        int d = dst[e];
        atomicAdd(&deg[d], w[e]);
        atomicAdd(&cnt[d], 1);
    }
}

// ---------- prep: dinv = rsqrt(deg+1); W1t[n][k] = bf16(W1[k][n]) ----------
__global__ __launch_bounds__(256) void k_prep(float* __restrict__ deg, const float* __restrict__ W1,
                                              u16* __restrict__ W1t) {
    int i = blockIdx.x * 256 + threadIdx.x;
    if (i < NNODES) deg[i] = rsqrtf(deg[i] + 1.0f);
    if (i < NFEAT * NHID) {
        int k = i >> 7, n = i & 127;
        W1t[n * NFEAT + k] = f2bf(W1[i]);
    }
}

// ---------- scan level 1 ----------
__global__ __launch_bounds__(SCAN_B) void k_scan1(const int* __restrict__ cnt, int* __restrict__ incl,
                                                  int* __restrict__ bsum) {
    __shared__ int sm[SCAN_B];
    int i = blockIdx.x * SCAN_B + threadIdx.x;
    int v = (i < NNODES) ? cnt[i] : 0;
    sm[threadIdx.x] = v;
    __syncthreads();
    for (int o = 1; o < SCAN_B; o <<= 1) {
        int t = (threadIdx.x >= (unsigned)o) ? sm[threadIdx.x - o] : 0;
        __syncthreads();
        sm[threadIdx.x] += t;
        __syncthreads();
    }
    if (i < NNODES) incl[i] = sm[threadIdx.x];
    if (threadIdx.x == SCAN_B - 1) bsum[blockIdx.x] = sm[threadIdx.x];
}

// ---------- scan level 2 ----------
__global__ __launch_bounds__(512) void k_scan2(int* __restrict__ bsum) {
    __shared__ int sm[512];
    int tid = threadIdx.x;
    int v = (tid < NB1) ? bsum[tid] : 0;
    sm[tid] = v;
    __syncthreads();
    for (int o = 1; o < 512; o <<= 1) {
        int t = (tid >= o) ? sm[tid - o] : 0;
        __syncthreads();
        sm[tid] += t;
        __syncthreads();
    }
    if (tid < NB1) bsum[tid] = sm[tid] - v;
}

// ---------- scan level 3 ----------
__global__ __launch_bounds__(256) void k_scan3(const int* __restrict__ incl, const int* __restrict__ cnt,
                                               const int* __restrict__ boff, int* __restrict__ rowptr,
                                               int* __restrict__ cursor) {
    int i = blockIdx.x * 256 + threadIdx.x;
    if (i < NNODES) {
        int ex = incl[i] - cnt[i] + boff[i >> 8];
        rowptr[i] = ex;
        cursor[i] = ex;
        if (i == NNODES - 1) rowptr[NNODES] = ex + cnt[i];
    }
}

// ---------- scatter edges into packed CSR slots: ecsr[pos] = {src, norm-bits} ----------
__global__ __launch_bounds__(256) void k_scatter(const int* __restrict__ src, const int* __restrict__ dst,
                                                 const float* __restrict__ w, const float* __restrict__ dinv,
                                                 int* __restrict__ cursor, uint2* __restrict__ ecsr) {
    int e = blockIdx.x * 256 + threadIdx.x;
    if (e < NEDGES) {
        int s = src[e], d = dst[e];
        int pos = atomicAdd(&cursor[d], 1);
        float nv = dinv[s] * w[e] * dinv[d];
        ecsr[pos] = make_uint2((u32)s, __float_as_uint(nv));
    }
}

// ---------- GEMM1 (MFMA bf16): h1[N,128](bf16) = x[N,256] @ W1[256,128] ----------
__global__ __launch_bounds__(256) void k_gemm1(const float* __restrict__ x, const u16* __restrict__ W1t,
                                               u16* __restrict__ h1) {
    __shared__ u16 Asm[2][8192];   // [128 m][64 k] bf16, swizzled
    __shared__ u16 Bsm[2][8192];   // [128 n][64 k] bf16, swizzled
    const int tid  = threadIdx.x;
    const int lane = tid & 63;
    const int w    = tid >> 6;
    const int wm   = w >> 1, wn = w & 1;
    const int row16 = lane & 15, g = lane >> 4;
    const int m0   = blockIdx.x * 128;
    const int swz  = (row16 & 7) << 3;

    f32x4 acc[4][4];
#pragma unroll
    for (int i = 0; i < 4; ++i)
#pragma unroll
        for (int j = 0; j < 4; ++j) acc[i][j] = (f32x4){0.f, 0.f, 0.f, 0.f};

    float4 areg[8];

    auto loadA = [&](int k0) {
#pragma unroll
        for (int i = 0; i < 8; ++i) {
            int s = tid + i * 256;
            int row = s >> 4, c4 = s & 15;
            int gr = m0 + row;
            if (gr < NNODES) areg[i] = *(const float4*)(x + (size_t)gr * NFEAT + k0 + c4 * 4);
            else             areg[i] = make_float4(0.f, 0.f, 0.f, 0.f);
        }
    };
    auto writeA = [&](int buf) {
#pragma unroll
        for (int i = 0; i < 8; ++i) {
            int s = tid + i * 256;
            int row = s >> 4, c4 = s & 15;
            int idx = row * 64 + ((c4 * 4) ^ ((row & 7) << 3));
            us4 h;
            h.x = f2bf(areg[i].x); h.y = f2bf(areg[i].y);
            h.z = f2bf(areg[i].z); h.w = f2bf(areg[i].w);
            *(us4*)(&Asm[buf][idx]) = h;
        }
    };
    auto stageB = [&](int buf, int k0) {
#pragma unroll
        for (int it = 0; it < 4; ++it) {
            int lin = w * 2048 + it * 512;
            int n_l = (lin + lane * 8) >> 6;
            int c_l = lane & 7;
            int gofs = n_l * NFEAT + k0 + ((c_l ^ (n_l & 7)) << 3);
            gload_lds16(W1t + gofs, &Bsm[buf][lin]);
        }
    };
    auto compute = [&](int buf) {
#pragma unroll
        for (int kk2 = 0; kk2 < 2; ++kk2) {
            bf16x8 af[4], bfr[4];
#pragma unroll
            for (int f = 0; f < 4; ++f) {
                int m_l = wm * 64 + f * 16 + row16;
                af[f]  = *(const bf16x8*)(&Asm[buf][m_l * 64 + ((kk2 * 32 + g * 8) ^ swz)]);
                int n_l = wn * 64 + f * 16 + row16;
                bfr[f] = *(const bf16x8*)(&Bsm[buf][n_l * 64 + ((kk2 * 32 + g * 8) ^ swz)]);
            }
#pragma unroll
            for (int fm = 0; fm < 4; ++fm)
#pragma unroll
                for (int fn = 0; fn < 4; ++fn)
                    acc[fm][fn] = __builtin_amdgcn_mfma_f32_16x16x32_bf16(af[fm], bfr[fn], acc[fm][fn], 0, 0, 0);
        }
    };

    loadA(0);
    stageB(0, 0);
    writeA(0);
    __syncthreads();
    int buf = 0;
    for (int step = 0; step < 4; ++step) {
        if (step < 3) { loadA((step + 1) * 64); stageB(buf ^ 1, (step + 1) * 64); }
        compute(buf);
        if (step < 3) writeA(buf ^ 1);
        __syncthreads();
        buf ^= 1;
    }

#pragma unroll
    for (int fm = 0; fm < 4; ++fm) {
        int mg = m0 + wm * 64 + fm * 16 + g * 4;
#pragma unroll
        for (int r = 0; r < 4; ++r) {
            int m_glob = mg + r;
            if (m_glob < NNODES) {
                size_t base = (size_t)m_glob * NHID + wn * 64 + row16;
#pragma unroll
                for (int fn = 0; fn < 4; ++fn)
                    h1[base + fn * 16] = f2bf(acc[fm][fn][r]);
            }
        }
    }
}

// ---------- agg1 CSR: a1 = bf16(relu(sum_in + dinv^2*h1[row] + b1)), 4x unroll ----------
__global__ __launch_bounds__(256) void k_agg1_csr(const int* __restrict__ rowptr, const uint2* __restrict__ ecsr,
                                                  const u16* __restrict__ h1, const float* __restrict__ dinv,
                                                  const float* __restrict__ b1, u16* __restrict__ a1) {
    int node = (blockIdx.x * 256 + threadIdx.x) >> 6;
    int lane = threadIdx.x & 63;
    if (node >= NNODES) return;
    int beg = rowptr[node], end = rowptr[node + 1];
    float acc0 = 0.f, acc1 = 0.f;
    int j = beg;
    for (; j + 3 < end; j += 4) {
        uint2 e0 = ecsr[j], e1 = ecsr[j + 1], e2 = ecsr[j + 2], e3 = ecsr[j + 3];
        u32 u0 = *(const u32*)(h1 + (size_t)e0.x * NHID + lane * 2);
        u32 u1 = *(const u32*)(h1 + (size_t)e1.x * NHID + lane * 2);
        u32 u2 = *(const u32*)(h1 + (size_t)e2.x * NHID + lane * 2);
        u32 u3 = *(const u32*)(h1 + (size_t)e3.x * NHID + lane * 2);
        float n0 = __uint_as_float(e0.y), n1 = __uint_as_float(e1.y);
        float n2 = __uint_as_float(e2.y), n3 = __uint_as_float(e3.y);
        acc0 += n0 * bf2f(u0 & 0xffff) + n1 * bf2f(u1 & 0xffff)
              + n2 * bf2f(u2 & 0xffff) + n3 * bf2f(u3 & 0xffff);
        acc1 += n0 * bf2f(u0 >> 16) + n1 * bf2f(u1 >> 16)
              + n2 * bf2f(u2 >> 16) + n3 * bf2f(u3 >> 16);
    }
    for (; j < end; ++j) {
        uint2 e = ecsr[j];
        float nv = __uint_as_float(e.y);
        u32 u = *(const u32*)(h1 + (size_t)e.x * NHID + lane * 2);
        acc0 += nv * bf2f(u & 0xffff);
        acc1 += nv * bf2f(u >> 16);
    }
    float sl = dinv[node];
    sl = sl * sl;
    u32 us = *(const u32*)(h1 + (size_t)node * NHID + lane * 2);
    float2 bb = *(const float2*)(b1 + lane * 2);
    float r0 = fmaxf(acc0 + sl * bf2f(us & 0xffff) + bb.x, 0.f);
    float r1 = fmaxf(acc1 + sl * bf2f(us >> 16)    + bb.y, 0.f);
    u32 o = (u32)f2bf(r0) | ((u32)f2bf(r1) << 16);
    *(u32*)(a1 + (size_t)node * NHID + lane * 2) = o;
}

// ---------- GEMM2: h2p[N,48](bf16, padded) = a1[N,128](bf16) @ W2[128,41] ----------
__global__ __launch_bounds__(256) void k_gemm2(const u16* __restrict__ a1, const float* __restrict__ W2,
                                               u16* __restrict__ h2p) {
    int row = blockIdx.x * 256 + threadIdx.x;
    if (row >= NNODES) return;
    float acc[NCLASS];
#pragma unroll
    for (int c = 0; c < NCLASS; ++c) acc[c] = 0.f;
    const u16* ar = a1 + (size_t)row * NHID;
    for (int k = 0; k < NHID; k += 4) {
        uint2 u = *(const uint2*)(ar + k);
        float x0 = bf2f(u.x & 0xffff), x1 = bf2f(u.x >> 16);
        float x2 = bf2f(u.y & 0xffff), x3 = bf2f(u.y >> 16);
        const float* w0 = W2 + k * NCLASS;
#pragma unroll
        for (int c = 0; c < NCLASS; ++c)
            acc[c] += x0 * w0[c] + x1 * w0[NCLASS + c] + x2 * w0[2 * NCLASS + c] + x3 * w0[3 * NCLASS + c];
    }
    u32* o = (u32*)(h2p + (size_t)row * H2S);
#pragma unroll
    for (int c = 0; c < 20; ++c)
        o[c] = (u32)f2bf(acc[2 * c]) | ((u32)f2bf(acc[2 * c + 1]) << 16);
    h2p[(size_t)row * H2S + 40] = f2bf(acc[40]);
}

// ---------- agg2 CSR + fused log-softmax (bf16 gathers), 4x unroll ----------
__global__ __launch_bounds__(256) void k_agg2_csr(const int* __restrict__ rowptr, const uint2* __restrict__ ecsr,
                                                  const u16* __restrict__ h2p, const float* __restrict__ dinv,
                                                  const float* __restrict__ b2, float* __restrict__ out) {
    int node = (blockIdx.x * 256 + threadIdx.x) >> 6;
    int lane = threadIdx.x & 63;
    if (node >= NNODES) return;
    int beg = rowptr[node], end = rowptr[node + 1];
    float acc = 0.f;
    int j = beg;
    for (; j + 3 < end; j += 4) {
        uint2 e0 = ecsr[j], e1 = ecsr[j + 1], e2 = ecsr[j + 2], e3 = ecsr[j + 3];
        if (lane < NCLASS) {
            float h0 = bf2f(h2p[(size_t)e0.x * H2S + lane]);
            float h1v = bf2f(h2p[(size_t)e1.x * H2S + lane]);
            float h2v = bf2f(h2p[(size_t)e2.x * H2S + lane]);
            float h3 = bf2f(h2p[(size_t)e3.x * H2S + lane]);
            acc += __uint_as_float(e0.y) * h0 + __uint_as_float(e1.y) * h1v
                 + __uint_as_float(e2.y) * h2v + __uint_as_float(e3.y) * h3;
        }
    }
    for (; j < end; ++j) {
        uint2 e = ecsr[j];
        if (lane < NCLASS) acc += __uint_as_float(e.y) * bf2f(h2p[(size_t)e.x * H2S + lane]);
    }
    float sl = dinv[node];
    sl = sl * sl;
    float v = -1e30f;
    if (lane < NCLASS) v = acc + sl * bf2f(h2p[(size_t)node * H2S + lane]) + b2[lane];
    float m = v;
#pragma unroll
    for (int o = 32; o >= 1; o >>= 1) m = fmaxf(m, __shfl_xor(m, o));
    float ex = (lane < NCLASS) ? expf(v - m) : 0.f;
    float s_ = ex;
#pragma unroll
    for (int o = 32; o >= 1; o >>= 1) s_ += __shfl_xor(s_, o);
    float ls = logf(s_) + m;
    if (lane < NCLASS) out[(size_t)node * NCLASS + lane] = v - ls;
}

extern "C" void kernel_launch(void* const* d_in, const int* in_sizes, int n_in,
                              void* d_out, int out_size, void* d_ws, size_t ws_size,
                              hipStream_t stream) {
    const float* x  = (const float*)d_in[0];
    const int*   ei = (const int*)d_in[1];
    const float* ew = (const float*)d_in[2];
    const float* W1 = (const float*)d_in[3];
    const float* b1 = (const float*)d_in[4];
    const float* W2 = (const float*)d_in[5];
    const float* b2 = (const float*)d_in[6];
    float* out = (float*)d_out;
    const int* srcp = ei;
    const int* dstp = ei + NEDGES;

    char* ws = (char*)d_ws;
    auto take = [&](size_t bytes) {
        char* p = ws;
        ws += (bytes + 255) & ~(size_t)255;
        return p;
    };
    float* dinv   = (float*)take((size_t)NNODES * 4);
    int*   cnt    = (int*)take((size_t)NNODES * 4);
    int*   incl   = (int*)take((size_t)NNODES * 4);
    int*   bsum   = (int*)take((size_t)NB1 * 4);
    int*   rowptr = (int*)take((size_t)(NNODES + 1) * 4);
    int*   cursor = (int*)take((size_t)NNODES * 4);
    uint2* ecsr   = (uint2*)take((size_t)NEDGES * 8);
    u16*   W1t    = (u16*)take((size_t)NFEAT * NHID * 2);
    u16*   h1     = (u16*)take((size_t)NNODES * NHID * 2);
    u16*   a1     = (u16*)take((size_t)NNODES * NHID * 2);
    u16*   h2p    = (u16*)take((size_t)NNODES * H2S * 2);

    hipMemsetAsync(dinv, 0, (size_t)NNODES * 4, stream);
    hipMemsetAsync(cnt,  0, (size_t)NNODES * 4, stream);

    k_hist<<<(NEDGES + 255) / 256, 256, 0, stream>>>(dstp, ew, dinv, cnt);
    k_prep<<<(NNODES + 255) / 256, 256, 0, stream>>>(dinv, W1, W1t);
    k_scan1<<<NB1, SCAN_B, 0, stream>>>(cnt, incl, bsum);
    k_scan2<<<1, 512, 0, stream>>>(bsum);
    k_scan3<<<(NNODES + 255) / 256, 256, 0, stream>>>(incl, cnt, bsum, rowptr, cursor);
    k_scatter<<<(NEDGES + 255) / 256, 256, 0, stream>>>(srcp, dstp, ew, dinv, cursor, ecsr);
    k_gemm1<<<(NNODES + 127) / 128, 256, 0, stream>>>(x, W1t, h1);
    k_agg1_csr<<<(NNODES * 64 + 255) / 256, 256, 0, stream>>>(rowptr, ecsr, h1, dinv, b1, a1);
    k_gemm2<<<(NNODES + 255) / 256, 256, 0, stream>>>(a1, W2, h2p);
    k_agg2_csr<<<(NNODES * 64 + 255) / 256, 256, 0, stream>>>(rowptr, ecsr, h2p, dinv, b2, out);
}

// Round 5
// 555.321 us; speedup vs baseline: 3.8968x; 1.1306x over previous
//
#include <hip/hip_runtime.h>

#define NNODES 100000
#define NEDGES 1600000
#define NFEAT  256
#define NHID   128
#define NCLASS 41
#define H2S    48          // padded bf16 stride for h2 rows (96 B)
#define SCAN_B 256
#define NB1    ((NNODES + SCAN_B - 1) / SCAN_B)   // 391 scan blocks

typedef __attribute__((ext_vector_type(8))) short bf16x8;
typedef __attribute__((ext_vector_type(4))) float f32x4;
typedef __attribute__((ext_vector_type(4))) unsigned short us4;
typedef unsigned short u16;
typedef unsigned int u32;
typedef unsigned long long u64;

__device__ __forceinline__ float bf2f(u32 bits16) {
    union { u32 i; float f; } v; v.i = bits16 << 16; return v.f;
}
__device__ __forceinline__ u16 f2bf(float f) {            // round-to-nearest-even
    union { u32 i; float f; } v; v.f = f;
    return (u16)((v.i + 0x7fff + ((v.i >> 16) & 1)) >> 16);
}
__device__ __forceinline__ void gload_lds16(const u16* g, u16* l) {
    __builtin_amdgcn_global_load_lds((const __attribute__((address_space(1))) u32*)g,
                                     (__attribute__((address_space(3))) u32*)l, 16, 0, 0);
}

// ---------- hist: ONE u64 atomic per edge: {cnt:16 | fixedpoint-sum:48} ----------
// w in [0,1): w*2^32 < 2^32; max in-degree ~60 -> sum < 2^38 << 2^48; cnt < 2^16.
__global__ __launch_bounds__(256) void k_hist(const int* __restrict__ dst, const float* __restrict__ w,
                                              u64* __restrict__ hist) {
    int e = blockIdx.x * 256 + threadIdx.x;
    if (e < NEDGES) {
        u64 pack = ((u64)1 << 48) + (u64)(w[e] * 4294967296.0f);
        atomicAdd(&hist[dst[e]], pack);
    }
}

// ---------- scan level 1 + unpack dinv + W1t convert (fused) ----------
__global__ __launch_bounds__(SCAN_B) void k_scan1(const u64* __restrict__ hist, const float* __restrict__ W1,
                                                  u16* __restrict__ W1t, float* __restrict__ dinv,
                                                  int* __restrict__ incl, int* __restrict__ bsum) {
    __shared__ int sm[SCAN_B];
    int i = blockIdx.x * SCAN_B + threadIdx.x;
    int v = 0;
    if (i < NNODES) {
        u64 p = hist[i];
        v = (int)(p >> 48);
        dinv[i] = rsqrtf((float)(p & 0xFFFFFFFFFFFFULL) * (1.0f / 4294967296.0f) + 1.0f);
    }
    if (i < NFEAT * NHID) {                      // 32768 < grid size 100096
        int k = i >> 7, n = i & 127;
        W1t[n * NFEAT + k] = f2bf(W1[i]);
    }
    sm[threadIdx.x] = v;
    __syncthreads();
    for (int o = 1; o < SCAN_B; o <<= 1) {
        int t = (threadIdx.x >= (unsigned)o) ? sm[threadIdx.x - o] : 0;
        __syncthreads();
        sm[threadIdx.x] += t;
        __syncthreads();
    }
    if (i < NNODES) incl[i] = sm[threadIdx.x];
    if (threadIdx.x == SCAN_B - 1) bsum[blockIdx.x] = sm[threadIdx.x];
}

// ---------- scan level 2 ----------
__global__ __launch_bounds__(512) void k_scan2(int* __restrict__ bsum) {
    __shared__ int sm[512];
    int tid = threadIdx.x;
    int v = (tid < NB1) ? bsum[tid] : 0;
    sm[tid] = v;
    __syncthreads();
    for (int o = 1; o < 512; o <<= 1) {
        int t = (tid >= o) ? sm[tid - o] : 0;
        __syncthreads();
        sm[tid] += t;
        __syncthreads();
    }
    if (tid < NB1) bsum[tid] = sm[tid] - v;
}

// ---------- scan level 3: rowptr/cursor (cnt re-derived from hist) ----------
__global__ __launch_bounds__(256) void k_scan3(const int* __restrict__ incl, const u64* __restrict__ hist,
                                               const int* __restrict__ boff, int* __restrict__ rowptr,
                                               int* __restrict__ cursor) {
    int i = blockIdx.x * 256 + threadIdx.x;
    if (i < NNODES) {
        int cntv = (int)(hist[i] >> 48);
        int ex = incl[i] - cntv + boff[i >> 8];
        rowptr[i] = ex;
        cursor[i] = ex;
        if (i == NNODES - 1) rowptr[NNODES] = ex + cntv;
    }
}

// ---------- scatter edges into packed CSR slots: ecsr[pos] = {src, norm-bits} ----------
__global__ __launch_bounds__(256) void k_scatter(const int* __restrict__ src, const int* __restrict__ dst,
                                                 const float* __restrict__ w, const float* __restrict__ dinv,
                                                 int* __restrict__ cursor, uint2* __restrict__ ecsr) {
    int e = blockIdx.x * 256 + threadIdx.x;
    if (e < NEDGES) {
        int s = src[e], d = dst[e];
        int pos = atomicAdd(&cursor[d], 1);
        float nv = dinv[s] * w[e] * dinv[d];
        ecsr[pos] = make_uint2((u32)s, __float_as_uint(nv));
    }
}

// ---------- GEMM1 (MFMA bf16): h1[N,128](bf16) = x[N,256] @ W1[256,128] ----------
__global__ __launch_bounds__(256) void k_gemm1(const float* __restrict__ x, const u16* __restrict__ W1t,
                                               u16* __restrict__ h1) {
    __shared__ u16 Asm[2][8192];   // [128 m][64 k] bf16, swizzled
    __shared__ u16 Bsm[2][8192];   // [128 n][64 k] bf16, swizzled
    const int tid  = threadIdx.x;
    const int lane = tid & 63;
    const int w    = tid >> 6;
    const int wm   = w >> 1, wn = w & 1;
    const int row16 = lane & 15, g = lane >> 4;
    const int m0   = blockIdx.x * 128;
    const int swz  = (row16 & 7) << 3;

    f32x4 acc[4][4];
#pragma unroll
    for (int i = 0; i < 4; ++i)
#pragma unroll
        for (int j = 0; j < 4; ++j) acc[i][j] = (f32x4){0.f, 0.f, 0.f, 0.f};

    float4 areg[8];

    auto loadA = [&](int k0) {
#pragma unroll
        for (int i = 0; i < 8; ++i) {
            int s = tid + i * 256;
            int row = s >> 4, c4 = s & 15;
            int gr = m0 + row;
            if (gr < NNODES) areg[i] = *(const float4*)(x + (size_t)gr * NFEAT + k0 + c4 * 4);
            else             areg[i] = make_float4(0.f, 0.f, 0.f, 0.f);
        }
    };
    auto writeA = [&](int buf) {
#pragma unroll
        for (int i = 0; i < 8; ++i) {
            int s = tid + i * 256;
            int row = s >> 4, c4 = s & 15;
            int idx = row * 64 + ((c4 * 4) ^ ((row & 7) << 3));
            us4 h;
            h.x = f2bf(areg[i].x); h.y = f2bf(areg[i].y);
            h.z = f2bf(areg[i].z); h.w = f2bf(areg[i].w);
            *(us4*)(&Asm[buf][idx]) = h;
        }
    };
    auto stageB = [&](int buf, int k0) {
#pragma unroll
        for (int it = 0; it < 4; ++it) {
            int lin = w * 2048 + it * 512;
            int n_l = (lin + lane * 8) >> 6;
            int c_l = lane & 7;
            int gofs = n_l * NFEAT + k0 + ((c_l ^ (n_l & 7)) << 3);
            gload_lds16(W1t + gofs, &Bsm[buf][lin]);
        }
    };
    auto compute = [&](int buf) {
#pragma unroll
        for (int kk2 = 0; kk2 < 2; ++kk2) {
            bf16x8 af[4], bfr[4];
#pragma unroll
            for (int f = 0; f < 4; ++f) {
                int m_l = wm * 64 + f * 16 + row16;
                af[f]  = *(const bf16x8*)(&Asm[buf][m_l * 64 + ((kk2 * 32 + g * 8) ^ swz)]);
                int n_l = wn * 64 + f * 16 + row16;
                bfr[f] = *(const bf16x8*)(&Bsm[buf][n_l * 64 + ((kk2 * 32 + g * 8) ^ swz)]);
            }
#pragma unroll
            for (int fm = 0; fm < 4; ++fm)
#pragma unroll
                for (int fn = 0; fn < 4; ++fn)
                    acc[fm][fn] = __builtin_amdgcn_mfma_f32_16x16x32_bf16(af[fm], bfr[fn], acc[fm][fn], 0, 0, 0);
        }
    };

    loadA(0);
    stageB(0, 0);
    writeA(0);
    __syncthreads();
    int buf = 0;
    for (int step = 0; step < 4; ++step) {
        if (step < 3) { loadA((step + 1) * 64); stageB(buf ^ 1, (step + 1) * 64); }
        compute(buf);
        if (step < 3) writeA(buf ^ 1);
        __syncthreads();
        buf ^= 1;
    }

#pragma unroll
    for (int fm = 0; fm < 4; ++fm) {
        int mg = m0 + wm * 64 + fm * 16 + g * 4;
#pragma unroll
        for (int r = 0; r < 4; ++r) {
            int m_glob = mg + r;
            if (m_glob < NNODES) {
                size_t base = (size_t)m_glob * NHID + wn * 64 + row16;
#pragma unroll
                for (int fn = 0; fn < 4; ++fn)
                    h1[base + fn * 16] = f2bf(acc[fm][fn][r]);
            }
        }
    }
}

// ---------- agg1 CSR: a1 = bf16(relu(sum_in + dinv^2*h1[row] + b1)), 4x unroll ----------
__global__ __launch_bounds__(256) void k_agg1_csr(const int* __restrict__ rowptr, const uint2* __restrict__ ecsr,
                                                  const u16* __restrict__ h1, const float* __restrict__ dinv,
                                                  const float* __restrict__ b1, u16* __restrict__ a1) {
    int node = (blockIdx.x * 256 + threadIdx.x) >> 6;
    int lane = threadIdx.x & 63;
    if (node >= NNODES) return;
    int beg = rowptr[node], end = rowptr[node + 1];
    float acc0 = 0.f, acc1 = 0.f;
    int j = beg;
    for (; j + 3 < end; j += 4) {
        uint2 e0 = ecsr[j], e1 = ecsr[j + 1], e2 = ecsr[j + 2], e3 = ecsr[j + 3];
        u32 u0 = *(const u32*)(h1 + (size_t)e0.x * NHID + lane * 2);
        u32 u1 = *(const u32*)(h1 + (size_t)e1.x * NHID + lane * 2);
        u32 u2 = *(const u32*)(h1 + (size_t)e2.x * NHID + lane * 2);
        u32 u3 = *(const u32*)(h1 + (size_t)e3.x * NHID + lane * 2);
        float n0 = __uint_as_float(e0.y), n1 = __uint_as_float(e1.y);
        float n2 = __uint_as_float(e2.y), n3 = __uint_as_float(e3.y);
        acc0 += n0 * bf2f(u0 & 0xffff) + n1 * bf2f(u1 & 0xffff)
              + n2 * bf2f(u2 & 0xffff) + n3 * bf2f(u3 & 0xffff);
        acc1 += n0 * bf2f(u0 >> 16) + n1 * bf2f(u1 >> 16)
              + n2 * bf2f(u2 >> 16) + n3 * bf2f(u3 >> 16);
    }
    for (; j < end; ++j) {
        uint2 e = ecsr[j];
        float nv = __uint_as_float(e.y);
        u32 u = *(const u32*)(h1 + (size_t)e.x * NHID + lane * 2);
        acc0 += nv * bf2f(u & 0xffff);
        acc1 += nv * bf2f(u >> 16);
    }
    float sl = dinv[node];
    sl = sl * sl;
    u32 us = *(const u32*)(h1 + (size_t)node * NHID + lane * 2);
    float2 bb = *(const float2*)(b1 + lane * 2);
    float r0 = fmaxf(acc0 + sl * bf2f(us & 0xffff) + bb.x, 0.f);
    float r1 = fmaxf(acc1 + sl * bf2f(us >> 16)    + bb.y, 0.f);
    u32 o = (u32)f2bf(r0) | ((u32)f2bf(r1) << 16);
    *(u32*)(a1 + (size_t)node * NHID + lane * 2) = o;
}

// ---------- GEMM2: h2p[N,48](bf16, padded) = a1[N,128](bf16) @ W2[128,41] ----------
__global__ __launch_bounds__(256) void k_gemm2(const u16* __restrict__ a1, const float* __restrict__ W2,
                                               u16* __restrict__ h2p) {
    int row = blockIdx.x * 256 + threadIdx.x;
    if (row >= NNODES) return;
    float acc[NCLASS];
#pragma unroll
    for (int c = 0; c < NCLASS; ++c) acc[c] = 0.f;
    const u16* ar = a1 + (size_t)row * NHID;
    for (int k = 0; k < NHID; k += 4) {
        uint2 u = *(const uint2*)(ar + k);
        float x0 = bf2f(u.x & 0xffff), x1 = bf2f(u.x >> 16);
        float x2 = bf2f(u.y & 0xffff), x3 = bf2f(u.y >> 16);
        const float* w0 = W2 + k * NCLASS;
#pragma unroll
        for (int c = 0; c < NCLASS; ++c)
            acc[c] += x0 * w0[c] + x1 * w0[NCLASS + c] + x2 * w0[2 * NCLASS + c] + x3 * w0[3 * NCLASS + c];
    }
    u32* o = (u32*)(h2p + (size_t)row * H2S);
#pragma unroll
    for (int c = 0; c < 20; ++c)
        o[c] = (u32)f2bf(acc[2 * c]) | ((u32)f2bf(acc[2 * c + 1]) << 16);
    h2p[(size_t)row * H2S + 40] = f2bf(acc[40]);
}

// ---------- agg2 CSR + fused log-softmax (bf16 gathers), 4x unroll ----------
__global__ __launch_bounds__(256) void k_agg2_csr(const int* __restrict__ rowptr, const uint2* __restrict__ ecsr,
                                                  const u16* __restrict__ h2p, const float* __restrict__ dinv,
                                                  const float* __restrict__ b2, float* __restrict__ out) {
    int node = (blockIdx.x * 256 + threadIdx.x) >> 6;
    int lane = threadIdx.x & 63;
    if (node >= NNODES) return;
    int beg = rowptr[node], end = rowptr[node + 1];
    float acc = 0.f;
    int j = beg;
    for (; j + 3 < end; j += 4) {
        uint2 e0 = ecsr[j], e1 = ecsr[j + 1], e2 = ecsr[j + 2], e3 = ecsr[j + 3];
        if (lane < NCLASS) {
            float h0 = bf2f(h2p[(size_t)e0.x * H2S + lane]);
            float h1v = bf2f(h2p[(size_t)e1.x * H2S + lane]);
            float h2v = bf2f(h2p[(size_t)e2.x * H2S + lane]);
            float h3 = bf2f(h2p[(size_t)e3.x * H2S + lane]);
            acc += __uint_as_float(e0.y) * h0 + __uint_as_float(e1.y) * h1v
                 + __uint_as_float(e2.y) * h2v + __uint_as_float(e3.y) * h3;
        }
    }
    for (; j < end; ++j) {
        uint2 e = ecsr[j];
        if (lane < NCLASS) acc += __uint_as_float(e.y) * bf2f(h2p[(size_t)e.x * H2S + lane]);
    }
    float sl = dinv[node];
    sl = sl * sl;
    float v = -1e30f;
    if (lane < NCLASS) v = acc + sl * bf2f(h2p[(size_t)node * H2S + lane]) + b2[lane];
    float m = v;
#pragma unroll
    for (int o = 32; o >= 1; o >>= 1) m = fmaxf(m, __shfl_xor(m, o));
    float ex = (lane < NCLASS) ? expf(v - m) : 0.f;
    float s_ = ex;
#pragma unroll
    for (int o = 32; o >= 1; o >>= 1) s_ += __shfl_xor(s_, o);
    float ls = logf(s_) + m;
    if (lane < NCLASS) out[(size_t)node * NCLASS + lane] = v - ls;
}

extern "C" void kernel_launch(void* const* d_in, const int* in_sizes, int n_in,
                              void* d_out, int out_size, void* d_ws, size_t ws_size,
                              hipStream_t stream) {
    const float* x  = (const float*)d_in[0];
    const int*   ei = (const int*)d_in[1];
    const float* ew = (const float*)d_in[2];
    const float* W1 = (const float*)d_in[3];
    const float* b1 = (const float*)d_in[4];
    const float* W2 = (const float*)d_in[5];
    const float* b2 = (const float*)d_in[6];
    float* out = (float*)d_out;
    const int* srcp = ei;
    const int* dstp = ei + NEDGES;

    char* ws = (char*)d_ws;
    auto take = [&](size_t bytes) {
        char* p = ws;
        ws += (bytes + 255) & ~(size_t)255;
        return p;
    };
    u64*   hist   = (u64*)take((size_t)NNODES * 8);
    float* dinv   = (float*)take((size_t)NNODES * 4);
    int*   incl   = (int*)take((size_t)NNODES * 4);
    int*   bsum   = (int*)take((size_t)NB1 * 4);
    int*   rowptr = (int*)take((size_t)(NNODES + 1) * 4);
    int*   cursor = (int*)take((size_t)NNODES * 4);
    uint2* ecsr   = (uint2*)take((size_t)NEDGES * 8);
    u16*   W1t    = (u16*)take((size_t)NFEAT * NHID * 2);
    u16*   h1     = (u16*)take((size_t)NNODES * NHID * 2);
    u16*   a1     = (u16*)take((size_t)NNODES * NHID * 2);
    u16*   h2p    = (u16*)take((size_t)NNODES * H2S * 2);

    hipMemsetAsync(hist, 0, (size_t)NNODES * 8, stream);

    k_hist<<<(NEDGES + 255) / 256, 256, 0, stream>>>(dstp, ew, hist);
    k_scan1<<<NB1, SCAN_B, 0, stream>>>(hist, W1, W1t, dinv, incl, bsum);
    k_scan2<<<1, 512, 0, stream>>>(bsum);
    k_scan3<<<(NNODES + 255) / 256, 256, 0, stream>>>(incl, hist, bsum, rowptr, cursor);
    k_scatter<<<(NEDGES + 255) / 256, 256, 0, stream>>>(srcp, dstp, ew, dinv, cursor, ecsr);
    k_gemm1<<<(NNODES + 127) / 128, 256, 0, stream>>>(x, W1t, h1);
    k_agg1_csr<<<(NNODES * 64 + 255) / 256, 256, 0, stream>>>(rowptr, ecsr, h1, dinv, b1, a1);
    k_gemm2<<<(NNODES + 255) / 256, 256, 0, stream>>>(a1, W2, h2p);
    k_agg2_csr<<<(NNODES * 64 + 255) / 256, 256, 0, stream>>>(rowptr, ecsr, h2p, dinv, b2, out);
}

// Round 6
// 524.570 us; speedup vs baseline: 4.1252x; 1.0586x over previous
//
#include <hip/hip_runtime.h>

#define NNODES 100000
#define NEDGES 1600000
#define NFEAT  256
#define NHID   128
#define NCLASS 41
#define H2S    48          // padded bf16 stride for h2 rows (96 B)
#define SCAN_B 256
#define NB1    ((NNODES + SCAN_B - 1) / SCAN_B)   // 391 scan blocks

typedef __attribute__((ext_vector_type(8))) short bf16x8;
typedef __attribute__((ext_vector_type(4))) float f32x4;
typedef __attribute__((ext_vector_type(4))) unsigned short us4;
typedef unsigned short u16;
typedef unsigned int u32;
typedef unsigned long long u64;

__device__ __forceinline__ float bf2f(u32 bits16) {
    union { u32 i; float f; } v; v.i = bits16 << 16; return v.f;
}
__device__ __forceinline__ u16 f2bf(float f) {            // round-to-nearest-even
    union { u32 i; float f; } v; v.f = f;
    return (u16)((v.i + 0x7fff + ((v.i >> 16) & 1)) >> 16);
}
__device__ __forceinline__ void gload_lds16(const u16* g, u16* l) {
    __builtin_amdgcn_global_load_lds((const __attribute__((address_space(1))) u32*)g,
                                     (__attribute__((address_space(3))) u32*)l, 16, 0, 0);
}

// ---------- hist: ONE u64 atomic per edge {cnt:16 | fixedpoint-sum:48};
// returned old value's top 16 bits = this edge's within-dst rank ----------
__global__ __launch_bounds__(256) void k_hist(const int* __restrict__ dst, const float* __restrict__ w,
                                              u64* __restrict__ hist, u16* __restrict__ rank) {
    int e = blockIdx.x * 256 + threadIdx.x;
    if (e < NEDGES) {
        u64 pack = ((u64)1 << 48) + (u64)(w[e] * 4294967296.0f);
        u64 old = atomicAdd(&hist[dst[e]], pack);
        rank[e] = (u16)(old >> 48);
    }
}

// ---------- scan level 1 + unpack dinv + W1t convert (fused) ----------
__global__ __launch_bounds__(SCAN_B) void k_scan1(const u64* __restrict__ hist, const float* __restrict__ W1,
                                                  u16* __restrict__ W1t, float* __restrict__ dinv,
                                                  int* __restrict__ incl, int* __restrict__ bsum) {
    __shared__ int sm[SCAN_B];
    int i = blockIdx.x * SCAN_B + threadIdx.x;
    int v = 0;
    if (i < NNODES) {
        u64 p = hist[i];
        v = (int)(p >> 48);
        dinv[i] = rsqrtf((float)(p & 0xFFFFFFFFFFFFULL) * (1.0f / 4294967296.0f) + 1.0f);
    }
    if (i < NFEAT * NHID) {                      // 32768 < grid size 100096
        int k = i >> 7, n = i & 127;
        W1t[n * NFEAT + k] = f2bf(W1[i]);
    }
    sm[threadIdx.x] = v;
    __syncthreads();
    for (int o = 1; o < SCAN_B; o <<= 1) {
        int t = (threadIdx.x >= (unsigned)o) ? sm[threadIdx.x - o] : 0;
        __syncthreads();
        sm[threadIdx.x] += t;
        __syncthreads();
    }
    if (i < NNODES) incl[i] = sm[threadIdx.x];
    if (threadIdx.x == SCAN_B - 1) bsum[blockIdx.x] = sm[threadIdx.x];
}

// ---------- scan level 2 ----------
__global__ __launch_bounds__(512) void k_scan2(int* __restrict__ bsum) {
    __shared__ int sm[512];
    int tid = threadIdx.x;
    int v = (tid < NB1) ? bsum[tid] : 0;
    sm[tid] = v;
    __syncthreads();
    for (int o = 1; o < 512; o <<= 1) {
        int t = (tid >= o) ? sm[tid - o] : 0;
        __syncthreads();
        sm[tid] += t;
        __syncthreads();
    }
    if (tid < NB1) bsum[tid] = sm[tid] - v;
}

// ---------- scan level 3: rowptr only (cursor no longer needed) ----------
__global__ __launch_bounds__(256) void k_scan3(const int* __restrict__ incl, const u64* __restrict__ hist,
                                               const int* __restrict__ boff, int* __restrict__ rowptr) {
    int i = blockIdx.x * 256 + threadIdx.x;
    if (i < NNODES) {
        int cntv = (int)(hist[i] >> 48);
        int ex = incl[i] - cntv + boff[i >> 8];
        rowptr[i] = ex;
        if (i == NNODES - 1) rowptr[NNODES] = ex + cntv;
    }
}

// ---------- scatter (atomic-free): pos = rowptr[dst] + rank ----------
__global__ __launch_bounds__(256) void k_scatter(const int* __restrict__ src, const int* __restrict__ dst,
                                                 const float* __restrict__ w, const float* __restrict__ dinv,
                                                 const int* __restrict__ rowptr, const u16* __restrict__ rank,
                                                 uint2* __restrict__ ecsr) {
    int e = blockIdx.x * 256 + threadIdx.x;
    if (e < NEDGES) {
        int s = src[e], d = dst[e];
        int pos = rowptr[d] + (int)rank[e];
        float nv = dinv[s] * w[e] * dinv[d];
        ecsr[pos] = make_uint2((u32)s, __float_as_uint(nv));
    }
}

// ---------- GEMM1 (MFMA bf16): h1[N,128](bf16) = x[N,256] @ W1[256,128] ----------
__global__ __launch_bounds__(256) void k_gemm1(const float* __restrict__ x, const u16* __restrict__ W1t,
                                               u16* __restrict__ h1) {
    __shared__ u16 Asm[2][8192];   // [128 m][64 k] bf16, swizzled
    __shared__ u16 Bsm[2][8192];   // [128 n][64 k] bf16, swizzled
    const int tid  = threadIdx.x;
    const int lane = tid & 63;
    const int w    = tid >> 6;
    const int wm   = w >> 1, wn = w & 1;
    const int row16 = lane & 15, g = lane >> 4;
    const int m0   = blockIdx.x * 128;
    const int swz  = (row16 & 7) << 3;

    f32x4 acc[4][4];
#pragma unroll
    for (int i = 0; i < 4; ++i)
#pragma unroll
        for (int j = 0; j < 4; ++j) acc[i][j] = (f32x4){0.f, 0.f, 0.f, 0.f};

    float4 areg[8];

    auto loadA = [&](int k0) {
#pragma unroll
        for (int i = 0; i < 8; ++i) {
            int s = tid + i * 256;
            int row = s >> 4, c4 = s & 15;
            int gr = m0 + row;
            if (gr < NNODES) areg[i] = *(const float4*)(x + (size_t)gr * NFEAT + k0 + c4 * 4);
            else             areg[i] = make_float4(0.f, 0.f, 0.f, 0.f);
        }
    };
    auto writeA = [&](int buf) {
#pragma unroll
        for (int i = 0; i < 8; ++i) {
            int s = tid + i * 256;
            int row = s >> 4, c4 = s & 15;
            int idx = row * 64 + ((c4 * 4) ^ ((row & 7) << 3));
            us4 h;
            h.x = f2bf(areg[i].x); h.y = f2bf(areg[i].y);
            h.z = f2bf(areg[i].z); h.w = f2bf(areg[i].w);
            *(us4*)(&Asm[buf][idx]) = h;
        }
    };
    auto stageB = [&](int buf, int k0) {
#pragma unroll
        for (int it = 0; it < 4; ++it) {
            int lin = w * 2048 + it * 512;
            int n_l = (lin + lane * 8) >> 6;
            int c_l = lane & 7;
            int gofs = n_l * NFEAT + k0 + ((c_l ^ (n_l & 7)) << 3);
            gload_lds16(W1t + gofs, &Bsm[buf][lin]);
        }
    };
    auto compute = [&](int buf) {
#pragma unroll
        for (int kk2 = 0; kk2 < 2; ++kk2) {
            bf16x8 af[4], bfr[4];
#pragma unroll
            for (int f = 0; f < 4; ++f) {
                int m_l = wm * 64 + f * 16 + row16;
                af[f]  = *(const bf16x8*)(&Asm[buf][m_l * 64 + ((kk2 * 32 + g * 8) ^ swz)]);
                int n_l = wn * 64 + f * 16 + row16;
                bfr[f] = *(const bf16x8*)(&Bsm[buf][n_l * 64 + ((kk2 * 32 + g * 8) ^ swz)]);
            }
#pragma unroll
            for (int fm = 0; fm < 4; ++fm)
#pragma unroll
                for (int fn = 0; fn < 4; ++fn)
                    acc[fm][fn] = __builtin_amdgcn_mfma_f32_16x16x32_bf16(af[fm], bfr[fn], acc[fm][fn], 0, 0, 0);
        }
    };

    loadA(0);
    stageB(0, 0);
    writeA(0);
    __syncthreads();
    int buf = 0;
    for (int step = 0; step < 4; ++step) {
        if (step < 3) { loadA((step + 1) * 64); stageB(buf ^ 1, (step + 1) * 64); }
        compute(buf);
        if (step < 3) writeA(buf ^ 1);
        __syncthreads();
        buf ^= 1;
    }

#pragma unroll
    for (int fm = 0; fm < 4; ++fm) {
        int mg = m0 + wm * 64 + fm * 16 + g * 4;
#pragma unroll
        for (int r = 0; r < 4; ++r) {
            int m_glob = mg + r;
            if (m_glob < NNODES) {
                size_t base = (size_t)m_glob * NHID + wn * 64 + row16;
#pragma unroll
                for (int fn = 0; fn < 4; ++fn)
                    h1[base + fn * 16] = f2bf(acc[fm][fn][r]);
            }
        }
    }
}

// ---------- agg1 CSR: a1 = bf16(relu(sum_in + dinv^2*h1[row] + b1)), 4x unroll ----------
__global__ __launch_bounds__(256) void k_agg1_csr(const int* __restrict__ rowptr, const uint2* __restrict__ ecsr,
                                                  const u16* __restrict__ h1, const float* __restrict__ dinv,
                                                  const float* __restrict__ b1, u16* __restrict__ a1) {
    int node = (blockIdx.x * 256 + threadIdx.x) >> 6;
    int lane = threadIdx.x & 63;
    if (node >= NNODES) return;
    int beg = rowptr[node], end = rowptr[node + 1];
    float acc0 = 0.f, acc1 = 0.f;
    int j = beg;
    for (; j + 3 < end; j += 4) {
        uint2 e0 = ecsr[j], e1 = ecsr[j + 1], e2 = ecsr[j + 2], e3 = ecsr[j + 3];
        u32 u0 = *(const u32*)(h1 + (size_t)e0.x * NHID + lane * 2);
        u32 u1 = *(const u32*)(h1 + (size_t)e1.x * NHID + lane * 2);
        u32 u2 = *(const u32*)(h1 + (size_t)e2.x * NHID + lane * 2);
        u32 u3 = *(const u32*)(h1 + (size_t)e3.x * NHID + lane * 2);
        float n0 = __uint_as_float(e0.y), n1 = __uint_as_float(e1.y);
        float n2 = __uint_as_float(e2.y), n3 = __uint_as_float(e3.y);
        acc0 += n0 * bf2f(u0 & 0xffff) + n1 * bf2f(u1 & 0xffff)
              + n2 * bf2f(u2 & 0xffff) + n3 * bf2f(u3 & 0xffff);
        acc1 += n0 * bf2f(u0 >> 16) + n1 * bf2f(u1 >> 16)
              + n2 * bf2f(u2 >> 16) + n3 * bf2f(u3 >> 16);
    }
    for (; j < end; ++j) {
        uint2 e = ecsr[j];
        float nv = __uint_as_float(e.y);
        u32 u = *(const u32*)(h1 + (size_t)e.x * NHID + lane * 2);
        acc0 += nv * bf2f(u & 0xffff);
        acc1 += nv * bf2f(u >> 16);
    }
    float sl = dinv[node];
    sl = sl * sl;
    u32 us = *(const u32*)(h1 + (size_t)node * NHID + lane * 2);
    float2 bb = *(const float2*)(b1 + lane * 2);
    float r0 = fmaxf(acc0 + sl * bf2f(us & 0xffff) + bb.x, 0.f);
    float r1 = fmaxf(acc1 + sl * bf2f(us >> 16)    + bb.y, 0.f);
    u32 o = (u32)f2bf(r0) | ((u32)f2bf(r1) << 16);
    *(u32*)(a1 + (size_t)node * NHID + lane * 2) = o;
}

// ---------- GEMM2: h2p[N,48](bf16, padded) = a1[N,128](bf16) @ W2[128,41] ----------
__global__ __launch_bounds__(256) void k_gemm2(const u16* __restrict__ a1, const float* __restrict__ W2,
                                               u16* __restrict__ h2p) {
    int row = blockIdx.x * 256 + threadIdx.x;
    if (row >= NNODES) return;
    float acc[NCLASS];
#pragma unroll
    for (int c = 0; c < NCLASS; ++c) acc[c] = 0.f;
    const u16* ar = a1 + (size_t)row * NHID;
    for (int k = 0; k < NHID; k += 4) {
        uint2 u = *(const uint2*)(ar + k);
        float x0 = bf2f(u.x & 0xffff), x1 = bf2f(u.x >> 16);
        float x2 = bf2f(u.y & 0xffff), x3 = bf2f(u.y >> 16);
        const float* w0 = W2 + k * NCLASS;
#pragma unroll
        for (int c = 0; c < NCLASS; ++c)
            acc[c] += x0 * w0[c] + x1 * w0[NCLASS + c] + x2 * w0[2 * NCLASS + c] + x3 * w0[3 * NCLASS + c];
    }
    u32* o = (u32*)(h2p + (size_t)row * H2S);
#pragma unroll
    for (int c = 0; c < 20; ++c)
        o[c] = (u32)f2bf(acc[2 * c]) | ((u32)f2bf(acc[2 * c + 1]) << 16);
    h2p[(size_t)row * H2S + 40] = f2bf(acc[40]);
}

// ---------- agg2 CSR + fused log-softmax (bf16 gathers), 4x unroll ----------
__global__ __launch_bounds__(256) void k_agg2_csr(const int* __restrict__ rowptr, const uint2* __restrict__ ecsr,
                                                  const u16* __restrict__ h2p, const float* __restrict__ dinv,
                                                  const float* __restrict__ b2, float* __restrict__ out) {
    int node = (blockIdx.x * 256 + threadIdx.x) >> 6;
    int lane = threadIdx.x & 63;
    if (node >= NNODES) return;
    int beg = rowptr[node], end = rowptr[node + 1];
    float acc = 0.f;
    int j = beg;
    for (; j + 3 < end; j += 4) {
        uint2 e0 = ecsr[j], e1 = ecsr[j + 1], e2 = ecsr[j + 2], e3 = ecsr[j + 3];
        if (lane < NCLASS) {
            float h0 = bf2f(h2p[(size_t)e0.x * H2S + lane]);
            float h1v = bf2f(h2p[(size_t)e1.x * H2S + lane]);
            float h2v = bf2f(h2p[(size_t)e2.x * H2S + lane]);
            float h3 = bf2f(h2p[(size_t)e3.x * H2S + lane]);
            acc += __uint_as_float(e0.y) * h0 + __uint_as_float(e1.y) * h1v
                 + __uint_as_float(e2.y) * h2v + __uint_as_float(e3.y) * h3;
        }
    }
    for (; j < end; ++j) {
        uint2 e = ecsr[j];
        if (lane < NCLASS) acc += __uint_as_float(e.y) * bf2f(h2p[(size_t)e.x * H2S + lane]);
    }
    float sl = dinv[node];
    sl = sl * sl;
    float v = -1e30f;
    if (lane < NCLASS) v = acc + sl * bf2f(h2p[(size_t)node * H2S + lane]) + b2[lane];
    float m = v;
#pragma unroll
    for (int o = 32; o >= 1; o >>= 1) m = fmaxf(m, __shfl_xor(m, o));
    float ex = (lane < NCLASS) ? expf(v - m) : 0.f;
    float s_ = ex;
#pragma unroll
    for (int o = 32; o >= 1; o >>= 1) s_ += __shfl_xor(s_, o);
    float ls = logf(s_) + m;
    if (lane < NCLASS) out[(size_t)node * NCLASS + lane] = v - ls;
}

extern "C" void kernel_launch(void* const* d_in, const int* in_sizes, int n_in,
                              void* d_out, int out_size, void* d_ws, size_t ws_size,
                              hipStream_t stream) {
    const float* x  = (const float*)d_in[0];
    const int*   ei = (const int*)d_in[1];
    const float* ew = (const float*)d_in[2];
    const float* W1 = (const float*)d_in[3];
    const float* b1 = (const float*)d_in[4];
    const float* W2 = (const float*)d_in[5];
    const float* b2 = (const float*)d_in[6];
    float* out = (float*)d_out;
    const int* srcp = ei;
    const int* dstp = ei + NEDGES;

    char* ws = (char*)d_ws;
    auto take = [&](size_t bytes) {
        char* p = ws;
        ws += (bytes + 255) & ~(size_t)255;
        return p;
    };
    u64*   hist   = (u64*)take((size_t)NNODES * 8);
    u16*   rank   = (u16*)take((size_t)NEDGES * 2);
    float* dinv   = (float*)take((size_t)NNODES * 4);
    int*   incl   = (int*)take((size_t)NNODES * 4);
    int*   bsum   = (int*)take((size_t)NB1 * 4);
    int*   rowptr = (int*)take((size_t)(NNODES + 1) * 4);
    uint2* ecsr   = (uint2*)take((size_t)NEDGES * 8);
    u16*   W1t    = (u16*)take((size_t)NFEAT * NHID * 2);
    u16*   h1     = (u16*)take((size_t)NNODES * NHID * 2);
    u16*   a1     = (u16*)take((size_t)NNODES * NHID * 2);
    u16*   h2p    = (u16*)take((size_t)NNODES * H2S * 2);

    hipMemsetAsync(hist, 0, (size_t)NNODES * 8, stream);

    k_hist<<<(NEDGES + 255) / 256, 256, 0, stream>>>(dstp, ew, hist, rank);
    k_scan1<<<NB1, SCAN_B, 0, stream>>>(hist, W1, W1t, dinv, incl, bsum);
    k_scan2<<<1, 512, 0, stream>>>(bsum);
    k_scan3<<<(NNODES + 255) / 256, 256, 0, stream>>>(incl, hist, bsum, rowptr);
    k_scatter<<<(NEDGES + 255) / 256, 256, 0, stream>>>(srcp, dstp, ew, dinv, rowptr, rank, ecsr);
    k_gemm1<<<(NNODES + 127) / 128, 256, 0, stream>>>(x, W1t, h1);
    k_agg1_csr<<<(NNODES * 64 + 255) / 256, 256, 0, stream>>>(rowptr, ecsr, h1, dinv, b1, a1);
    k_gemm2<<<(NNODES + 255) / 256, 256, 0, stream>>>(a1, W2, h2p);
    k_agg2_csr<<<(NNODES * 64 + 255) / 256, 256, 0, stream>>>(rowptr, ecsr, h2p, dinv, b2, out);
}

// Round 8
// 478.591 us; speedup vs baseline: 4.5215x; 1.0961x over previous
//
#include <hip/hip_runtime.h>

#define NNODES 100000
#define NEDGES 1600000
#define NFEAT  256
#define NHID   128
#define NCLASS 41
#define H2S    48          // padded bf16 stride for h2 rows (96 B = 24 u32)
#define SCAN_B 256
#define NB1    ((NNODES + SCAN_B - 1) / SCAN_B)   // 391 scan blocks
#define XROWS  100096      // gemm1 grid rows (782 * 128), xb padded to this

typedef __attribute__((ext_vector_type(8))) short bf16x8;
typedef __attribute__((ext_vector_type(4))) float f32x4;
typedef __attribute__((ext_vector_type(8))) unsigned short us8;
typedef unsigned short u16;
typedef unsigned int u32;
typedef unsigned long long u64;

__device__ __forceinline__ float bf2f(u32 bits16) {
    union { u32 i; float f; } v; v.i = bits16 << 16; return v.f;
}
__device__ __forceinline__ u16 f2bf(float f) {            // round-to-nearest-even
    union { u32 i; float f; } v; v.f = f;
    return (u16)((v.i + 0x7fff + ((v.i >> 16) & 1)) >> 16);
}
__device__ __forceinline__ void gload_lds16(const u16* g, u16* l) {
    __builtin_amdgcn_global_load_lds((const __attribute__((address_space(1))) u32*)g,
                                     (__attribute__((address_space(3))) u32*)l, 16, 0, 0);
}

// ---------- hist: ONE u64 atomic per edge {cnt:16 | fixedpoint-sum:48};
// old value's top 16 bits = within-dst rank. FUSED: x fp32 -> xb bf16
// (streaming uses the read BW + VALU this atomic-bound kernel leaves idle) ----------
__global__ __launch_bounds__(256) void k_hist(const int* __restrict__ dst, const float* __restrict__ w,
                                              u64* __restrict__ hist, u16* __restrict__ rank,
                                              const float* __restrict__ x, u16* __restrict__ xb) {
    int e = blockIdx.x * 256 + threadIdx.x;
    if (e < NEDGES) {
        u64 pack = ((u64)1 << 48) + (u64)(w[e] * 4294967296.0f);
        u64 old = atomicAdd(&hist[dst[e]], pack);
        rank[e] = (u16)(old >> 48);
    }
    size_t base = (size_t)e * 16;              // 1.6M threads * 16 = 25.6M elems exactly
    if (base < (size_t)NNODES * NFEAT) {
        float4 v0 = *(const float4*)(x + base);
        float4 v1 = *(const float4*)(x + base + 4);
        float4 v2 = *(const float4*)(x + base + 8);
        float4 v3 = *(const float4*)(x + base + 12);
        us8 h0 = {f2bf(v0.x), f2bf(v0.y), f2bf(v0.z), f2bf(v0.w),
                  f2bf(v1.x), f2bf(v1.y), f2bf(v1.z), f2bf(v1.w)};
        us8 h1 = {f2bf(v2.x), f2bf(v2.y), f2bf(v2.z), f2bf(v2.w),
                  f2bf(v3.x), f2bf(v3.y), f2bf(v3.z), f2bf(v3.w)};
        *(us8*)(xb + base)     = h0;
        *(us8*)(xb + base + 8) = h1;
    }
}

// ---------- scan level 1 + unpack dinv + W1t convert (fused) ----------
__global__ __launch_bounds__(SCAN_B) void k_scan1(const u64* __restrict__ hist, const float* __restrict__ W1,
                                                  u16* __restrict__ W1t, float* __restrict__ dinv,
                                                  int* __restrict__ incl, int* __restrict__ bsum) {
    __shared__ int sm[SCAN_B];
    int i = blockIdx.x * SCAN_B + threadIdx.x;
    int v = 0;
    if (i < NNODES) {
        u64 p = hist[i];
        v = (int)(p >> 48);
        dinv[i] = rsqrtf((float)(p & 0xFFFFFFFFFFFFULL) * (1.0f / 4294967296.0f) + 1.0f);
    }
    if (i < NFEAT * NHID) {
        int k = i >> 7, n = i & 127;
        W1t[n * NFEAT + k] = f2bf(W1[i]);
    }
    sm[threadIdx.x] = v;
    __syncthreads();
    for (int o = 1; o < SCAN_B; o <<= 1) {
        int t = (threadIdx.x >= (unsigned)o) ? sm[threadIdx.x - o] : 0;
        __syncthreads();
        sm[threadIdx.x] += t;
        __syncthreads();
    }
    if (i < NNODES) incl[i] = sm[threadIdx.x];
    if (threadIdx.x == SCAN_B - 1) bsum[blockIdx.x] = sm[threadIdx.x];
}

// ---------- scan level 2 ----------
__global__ __launch_bounds__(512) void k_scan2(int* __restrict__ bsum) {
    __shared__ int sm[512];
    int tid = threadIdx.x;
    int v = (tid < NB1) ? bsum[tid] : 0;
    sm[tid] = v;
    __syncthreads();
    for (int o = 1; o < 512; o <<= 1) {
        int t = (tid >= o) ? sm[tid - o] : 0;
        __syncthreads();
        sm[tid] += t;
        __syncthreads();
    }
    if (tid < NB1) bsum[tid] = sm[tid] - v;
}

// ---------- scan level 3: rowptr ----------
__global__ __launch_bounds__(256) void k_scan3(const int* __restrict__ incl, const u64* __restrict__ hist,
                                               const int* __restrict__ boff, int* __restrict__ rowptr) {
    int i = blockIdx.x * 256 + threadIdx.x;
    if (i < NNODES) {
        int cntv = (int)(hist[i] >> 48);
        int ex = incl[i] - cntv + boff[i >> 8];
        rowptr[i] = ex;
        if (i == NNODES - 1) rowptr[NNODES] = ex + cntv;
    }
}

// ---------- scatter (atomic-free): pos = rowptr[dst] + rank ----------
__global__ __launch_bounds__(256) void k_scatter(const int* __restrict__ src, const int* __restrict__ dst,
                                                 const float* __restrict__ w, const float* __restrict__ dinv,
                                                 const int* __restrict__ rowptr, const u16* __restrict__ rank,
                                                 uint2* __restrict__ ecsr) {
    int e = blockIdx.x * 256 + threadIdx.x;
    if (e < NEDGES) {
        int s = src[e], d = dst[e];
        int pos = rowptr[d] + (int)rank[e];
        float nv = dinv[s] * w[e] * dinv[d];
        ecsr[pos] = make_uint2((u32)s, __float_as_uint(nv));
    }
}

// ---------- GEMM1 (MFMA bf16, m97-style): h1 = xb @ W1t^T ----------
// Both A and B staged via global_load_lds w16 with pre-swizzled SOURCE; no reg staging.
__global__ __launch_bounds__(256) void k_gemm1(const u16* __restrict__ xb, const u16* __restrict__ W1t,
                                               u16* __restrict__ h1) {
    __shared__ u16 Asm[2][8192];   // [128 m][64 k] bf16, swizzled
    __shared__ u16 Bsm[2][8192];   // [128 n][64 k] bf16, swizzled
    const int tid  = threadIdx.x;
    const int lane = tid & 63;
    const int w    = tid >> 6;
    const int wm   = w >> 1, wn = w & 1;
    const int row16 = lane & 15, g = lane >> 4;
    const int m0   = blockIdx.x * 128;
    const int swz  = (row16 & 7) << 3;

    f32x4 acc[4][4];
#pragma unroll
    for (int i = 0; i < 4; ++i)
#pragma unroll
        for (int j = 0; j < 4; ++j) acc[i][j] = (f32x4){0.f, 0.f, 0.f, 0.f};

    auto stageA = [&](int buf, int k0) {
#pragma unroll
        for (int it = 0; it < 4; ++it) {
            int lin = w * 2048 + it * 512;              // wave-uniform ushort base
            int row = (lin + lane * 8) >> 6;            // 64 ushorts per row
            int c_l = lane & 7;
            int gofs = (m0 + row) * NFEAT + k0 + ((c_l ^ (row & 7)) << 3);
            gload_lds16(xb + gofs, &Asm[buf][lin]);     // xb padded to XROWS: no OOB
        }
    };
    auto stageB = [&](int buf, int k0) {
#pragma unroll
        for (int it = 0; it < 4; ++it) {
            int lin = w * 2048 + it * 512;
            int n_l = (lin + lane * 8) >> 6;
            int c_l = lane & 7;
            int gofs = n_l * NFEAT + k0 + ((c_l ^ (n_l & 7)) << 3);
            gload_lds16(W1t + gofs, &Bsm[buf][lin]);
        }
    };
    auto compute = [&](int buf) {
#pragma unroll
        for (int kk2 = 0; kk2 < 2; ++kk2) {
            bf16x8 af[4], bfr[4];
#pragma unroll
            for (int f = 0; f < 4; ++f) {
                int m_l = wm * 64 + f * 16 + row16;
                af[f]  = *(const bf16x8*)(&Asm[buf][m_l * 64 + ((kk2 * 32 + g * 8) ^ swz)]);
                int n_l = wn * 64 + f * 16 + row16;
                bfr[f] = *(const bf16x8*)(&Bsm[buf][n_l * 64 + ((kk2 * 32 + g * 8) ^ swz)]);
            }
#pragma unroll
            for (int fm = 0; fm < 4; ++fm)
#pragma unroll
                for (int fn = 0; fn < 4; ++fn)
                    acc[fm][fn] = __builtin_amdgcn_mfma_f32_16x16x32_bf16(af[fm], bfr[fn], acc[fm][fn], 0, 0, 0);
        }
    };

    stageA(0, 0);
    stageB(0, 0);
    __syncthreads();
    int buf = 0;
    for (int step = 0; step < 4; ++step) {
        if (step < 3) { stageA(buf ^ 1, (step + 1) * 64); stageB(buf ^ 1, (step + 1) * 64); }
        compute(buf);
        __syncthreads();
        buf ^= 1;
    }

    // C/D layout: col=lane&15, row=(lane>>4)*4+reg (m89-verified)
#pragma unroll
    for (int fm = 0; fm < 4; ++fm) {
        int mg = m0 + wm * 64 + fm * 16 + g * 4;
#pragma unroll
        for (int r = 0; r < 4; ++r) {
            int m_glob = mg + r;
            if (m_glob < NNODES) {
                size_t base = (size_t)m_glob * NHID + wn * 64 + row16;
#pragma unroll
                for (int fn = 0; fn < 4; ++fn)
                    h1[base + fn * 16] = f2bf(acc[fm][fn][r]);
            }
        }
    }
}

// ---------- agg1 CSR: a1 = bf16(relu(sum_in + dinv^2*h1[row] + b1)), 4x unroll ----------
__global__ __launch_bounds__(256) void k_agg1_csr(const int* __restrict__ rowptr, const uint2* __restrict__ ecsr,
                                                  const u16* __restrict__ h1, const float* __restrict__ dinv,
                                                  const float* __restrict__ b1, u16* __restrict__ a1) {
    int node = (blockIdx.x * 256 + threadIdx.x) >> 6;
    int lane = threadIdx.x & 63;
    if (node >= NNODES) return;
    int beg = rowptr[node], end = rowptr[node + 1];
    float acc0 = 0.f, acc1 = 0.f;
    int j = beg;
    for (; j + 3 < end; j += 4) {
        uint2 e0 = ecsr[j], e1 = ecsr[j + 1], e2 = ecsr[j + 2], e3 = ecsr[j + 3];
        u32 u0 = *(const u32*)(h1 + (size_t)e0.x * NHID + lane * 2);
        u32 u1 = *(const u32*)(h1 + (size_t)e1.x * NHID + lane * 2);
        u32 u2 = *(const u32*)(h1 + (size_t)e2.x * NHID + lane * 2);
        u32 u3 = *(const u32*)(h1 + (size_t)e3.x * NHID + lane * 2);
        float n0 = __uint_as_float(e0.y), n1 = __uint_as_float(e1.y);
        float n2 = __uint_as_float(e2.y), n3 = __uint_as_float(e3.y);
        acc0 += n0 * bf2f(u0 & 0xffff) + n1 * bf2f(u1 & 0xffff)
              + n2 * bf2f(u2 & 0xffff) + n3 * bf2f(u3 & 0xffff);
        acc1 += n0 * bf2f(u0 >> 16) + n1 * bf2f(u1 >> 16)
              + n2 * bf2f(u2 >> 16) + n3 * bf2f(u3 >> 16);
    }
    for (; j < end; ++j) {
        uint2 e = ecsr[j];
        float nv = __uint_as_float(e.y);
        u32 u = *(const u32*)(h1 + (size_t)e.x * NHID + lane * 2);
        acc0 += nv * bf2f(u & 0xffff);
        acc1 += nv * bf2f(u >> 16);
    }
    float sl = dinv[node];
    sl = sl * sl;
    u32 us = *(const u32*)(h1 + (size_t)node * NHID + lane * 2);
    float2 bb = *(const float2*)(b1 + lane * 2);
    float r0 = fmaxf(acc0 + sl * bf2f(us & 0xffff) + bb.x, 0.f);
    float r1 = fmaxf(acc1 + sl * bf2f(us >> 16)    + bb.y, 0.f);
    u32 o = (u32)f2bf(r0) | ((u32)f2bf(r1) << 16);
    *(u32*)(a1 + (size_t)node * NHID + lane * 2) = o;
}

// ---------- GEMM2: h2p[N,48](bf16, padded, pad zeroed) = a1 @ W2 ----------
__global__ __launch_bounds__(256) void k_gemm2(const u16* __restrict__ a1, const float* __restrict__ W2,
                                               u16* __restrict__ h2p) {
    int row = blockIdx.x * 256 + threadIdx.x;
    if (row >= NNODES) return;
    float acc[NCLASS];
#pragma unroll
    for (int c = 0; c < NCLASS; ++c) acc[c] = 0.f;
    const u16* ar = a1 + (size_t)row * NHID;
    for (int k = 0; k < NHID; k += 4) {
        uint2 u = *(const uint2*)(ar + k);
        float x0 = bf2f(u.x & 0xffff), x1 = bf2f(u.x >> 16);
        float x2 = bf2f(u.y & 0xffff), x3 = bf2f(u.y >> 16);
        const float* w0 = W2 + k * NCLASS;
#pragma unroll
        for (int c = 0; c < NCLASS; ++c)
            acc[c] += x0 * w0[c] + x1 * w0[NCLASS + c] + x2 * w0[2 * NCLASS + c] + x3 * w0[3 * NCLASS + c];
    }
    u32* o = (u32*)(h2p + (size_t)row * H2S);
#pragma unroll
    for (int c = 0; c < 20; ++c)
        o[c] = (u32)f2bf(acc[2 * c]) | ((u32)f2bf(acc[2 * c + 1]) << 16);
    o[20] = (u32)f2bf(acc[40]);              // upper 16 bits zeroed (clean pad)
}

// ---------- agg2 CSR + log-softmax: 2 nodes/wave, 32-lane groups, u32-paired ----------
__global__ __launch_bounds__(256) void k_agg2_csr(const int* __restrict__ rowptr, const uint2* __restrict__ ecsr,
                                                  const u32* __restrict__ h2p32, const float* __restrict__ dinv,
                                                  const float* __restrict__ b2, float* __restrict__ out) {
    int wid  = (blockIdx.x * 256 + threadIdx.x) >> 6;
    int node = wid * 2 + ((threadIdx.x >> 5) & 1);
    int l    = threadIdx.x & 31;
    if (node >= NNODES) return;
    int c0 = l * 2, c1 = c0 + 1;
    bool ok0 = (c0 < NCLASS), ok1 = (c1 < NCLASS);
    int beg = rowptr[node], end = rowptr[node + 1];
    float acc0 = 0.f, acc1 = 0.f;
    int j = beg;
    for (; j + 3 < end; j += 4) {
        uint2 e0 = ecsr[j], e1 = ecsr[j + 1], e2 = ecsr[j + 2], e3 = ecsr[j + 3];
        if (ok0) {
            u32 u0 = h2p32[(size_t)e0.x * 24 + l];
            u32 u1 = h2p32[(size_t)e1.x * 24 + l];
            u32 u2 = h2p32[(size_t)e2.x * 24 + l];
            u32 u3 = h2p32[(size_t)e3.x * 24 + l];
            float n0 = __uint_as_float(e0.y), n1 = __uint_as_float(e1.y);
            float n2 = __uint_as_float(e2.y), n3 = __uint_as_float(e3.y);
            acc0 += n0 * bf2f(u0 & 0xffff) + n1 * bf2f(u1 & 0xffff)
                  + n2 * bf2f(u2 & 0xffff) + n3 * bf2f(u3 & 0xffff);
            acc1 += n0 * bf2f(u0 >> 16) + n1 * bf2f(u1 >> 16)
                  + n2 * bf2f(u2 >> 16) + n3 * bf2f(u3 >> 16);
        }
    }
    for (; j < end; ++j) {
        uint2 e = ecsr[j];
        if (ok0) {
            u32 u = h2p32[(size_t)e.x * 24 + l];
            float nv = __uint_as_float(e.y);
            acc0 += nv * bf2f(u & 0xffff);
            acc1 += nv * bf2f(u >> 16);
        }
    }
    float sl = dinv[node];
    sl = sl * sl;
    float v0 = -1e30f, v1 = -1e30f;
    if (ok0) {
        u32 u = h2p32[(size_t)node * 24 + l];
        v0 = acc0 + sl * bf2f(u & 0xffff) + b2[c0];
        if (ok1) v1 = acc1 + sl * bf2f(u >> 16) + b2[c1];
    }
    float m = fmaxf(v0, v1);
#pragma unroll
    for (int o = 16; o >= 1; o >>= 1) m = fmaxf(m, __shfl_xor(m, o, 32));
    float ex = (ok0 ? expf(v0 - m) : 0.f) + (ok1 ? expf(v1 - m) : 0.f);
#pragma unroll
    for (int o = 16; o >= 1; o >>= 1) ex += __shfl_xor(ex, o, 32);
    float ls = logf(ex) + m;
    if (ok0) out[(size_t)node * NCLASS + c0] = v0 - ls;
    if (ok1) out[(size_t)node * NCLASS + c1] = v1 - ls;
}

extern "C" void kernel_launch(void* const* d_in, const int* in_sizes, int n_in,
                              void* d_out, int out_size, void* d_ws, size_t ws_size,
                              hipStream_t stream) {
    const float* x  = (const float*)d_in[0];
    const int*   ei = (const int*)d_in[1];
    const float* ew = (const float*)d_in[2];
    const float* W1 = (const float*)d_in[3];
    const float* b1 = (const float*)d_in[4];
    const float* W2 = (const float*)d_in[5];
    const float* b2 = (const float*)d_in[6];
    float* out = (float*)d_out;
    const int* srcp = ei;
    const int* dstp = ei + NEDGES;

    char* ws = (char*)d_ws;
    auto take = [&](size_t bytes) {
        char* p = ws;
        ws += (bytes + 255) & ~(size_t)255;
        return p;
    };
    u64*   hist   = (u64*)take((size_t)NNODES * 8);
    u16*   rank   = (u16*)take((size_t)NEDGES * 2);
    float* dinv   = (float*)take((size_t)NNODES * 4);
    int*   incl   = (int*)take((size_t)NNODES * 4);
    int*   bsum   = (int*)take((size_t)NB1 * 4);
    int*   rowptr = (int*)take((size_t)(NNODES + 1) * 4);
    uint2* ecsr   = (uint2*)take((size_t)NEDGES * 8);
    u16*   W1t    = (u16*)take((size_t)NFEAT * NHID * 2);
    u16*   h1     = (u16*)take((size_t)NNODES * NHID * 2);
    // aliased region: xb (dead after gemm1) overlaps a1 + h2p
    size_t xb_bytes  = (size_t)XROWS * NFEAT * 2;            // 51.25 MB
    size_t a1_bytes  = (size_t)NNODES * NHID * 2;            // 25.6 MB (256-aligned)
    char*  region    = take(xb_bytes);
    u16*   xb  = (u16*)region;
    u16*   a1  = (u16*)region;                               // written after xb is dead
    u16*   h2p = (u16*)(region + a1_bytes);                  // beyond a1, within region

    hipMemsetAsync(hist, 0, (size_t)NNODES * 8, stream);

    k_hist<<<(NEDGES + 255) / 256, 256, 0, stream>>>(dstp, ew, hist, rank, x, xb);
    k_scan1<<<NB1, SCAN_B, 0, stream>>>(hist, W1, W1t, dinv, incl, bsum);
    k_scan2<<<1, 512, 0, stream>>>(bsum);
    k_scan3<<<(NNODES + 255) / 256, 256, 0, stream>>>(incl, hist, bsum, rowptr);
    k_scatter<<<(NEDGES + 255) / 256, 256, 0, stream>>>(srcp, dstp, ew, dinv, rowptr, rank, ecsr);
    k_gemm1<<<(NNODES + 127) / 128, 256, 0, stream>>>(xb, W1t, h1);
    k_agg1_csr<<<(NNODES * 64 + 255) / 256, 256, 0, stream>>>(rowptr, ecsr, h1, dinv, b1, a1);
    k_gemm2<<<(NNODES + 255) / 256, 256, 0, stream>>>(a1, W2, h2p);
    k_agg2_csr<<<(NNODES / 2 * 64 + 255) / 256, 256, 0, stream>>>(rowptr, ecsr, (const u32*)h2p, dinv, b2, out);
}